// Round 7
// baseline (433.486 us; speedup 1.0000x reference)
//
#include <hip/hip_runtime.h>
#include <cmath>

typedef unsigned short ushort_t;
typedef __bf16 bf16x8 __attribute__((ext_vector_type(8)));
typedef float  f32x4  __attribute__((ext_vector_type(4)));

#define B_  8
#define S_  2048
#define D_  768
#define MROWS (B_ * S_)       // 16384
#define EPS 1e-5f
#define LDST 40               // padded stride for fallback gemm only

__device__ __forceinline__ float b2f(ushort_t u) {
    union { unsigned int i; float f; } v; v.i = ((unsigned int)u) << 16; return v.f;
}
__device__ __forceinline__ ushort_t f2b(float f) {
    union { float f; unsigned int i; } v; v.f = f;
    unsigned int r = v.i + 0x7fffu + ((v.i >> 16) & 1u);
    return (ushort_t)(r >> 16);
}

// async 16B global->LDS; LDS dest = wave-uniform base + lane*16
__device__ __forceinline__ void gload16(const ushort_t* g, ushort_t* l) {
    __builtin_amdgcn_global_load_lds((__attribute__((address_space(1))) void*)g,
                                     (__attribute__((address_space(3))) void*)l,
                                     16, 0, 0);
}

// fp32 -> bf16 cast, 4 elems/thread
__global__ void cast_f32_bf16(const float* __restrict__ in, ushort_t* __restrict__ outp, long n)
{
    const long i = ((long)blockIdx.x * 256 + threadIdx.x) * 4;
    if (i + 3 < n) {
        const float4 v = *(const float4*)(in + i);
        ushort4 o;
        o.x = f2b(v.x); o.y = f2b(v.y); o.z = f2b(v.z); o.w = f2b(v.w);
        *(ushort4*)(outp + i) = o;
    }
}

// ---------------------------------------------------------------------------
// transpose (+optional fp32->bf16 cast): dst[C][R] = cvt(src[R][C]), z-batched
// (kept for fallback path)
// ---------------------------------------------------------------------------
template<int F32IN>
__global__ void transpose_any(const void* __restrict__ srcv, ushort_t* __restrict__ dst,
                              int R, int C, long sb, long db)
{
    __shared__ ushort_t tile[64 * 65];
    dst += (long)blockIdx.z * db;
    const int r0 = blockIdx.y * 64, c0 = blockIdx.x * 64;
    const int t = threadIdx.x;
    const int tr = t >> 6, tc = t & 63;
    #pragma unroll
    for (int i = 0; i < 16; i++) {
        const int r = i * 4 + tr;
        ushort_t v;
        if (F32IN) v = f2b(((const float*)srcv + (long)blockIdx.z * sb)[(long)(r0 + r) * C + (c0 + tc)]);
        else       v = ((const ushort_t*)srcv + (long)blockIdx.z * sb)[(long)(r0 + r) * C + (c0 + tc)];
        tile[r * 65 + tc] = v;
    }
    __syncthreads();
    #pragma unroll
    for (int i = 0; i < 16; i++) {
        const int r = i * 4 + tr;
        dst[(long)(c0 + r) * R + (r0 + tc)] = tile[tc * 65 + r];
    }
}

// all four 768x768 weight transposes in ONE dispatch (z selects the weight;
// dst buffers are contiguous at stride 768*768)
__global__ void transpose_w4(const float* __restrict__ w0, const float* __restrict__ w1,
                             const float* __restrict__ w2, const float* __restrict__ w3,
                             ushort_t* __restrict__ dst)
{
    __shared__ ushort_t tile[64 * 65];
    const float* src = (blockIdx.z == 0) ? w0 : (blockIdx.z == 1) ? w1
                     : (blockIdx.z == 2) ? w2 : w3;
    dst += (size_t)blockIdx.z * ((size_t)768 * 768);
    const int r0 = blockIdx.y * 64, c0 = blockIdx.x * 64;
    const int t = threadIdx.x;
    const int tr = t >> 6, tc = t & 63;
    #pragma unroll
    for (int i = 0; i < 16; i++) {
        const int r = i * 4 + tr;
        tile[r * 65 + tc] = f2b(src[(long)(r0 + r) * 768 + (c0 + tc)]);
    }
    __syncthreads();
    #pragma unroll
    for (int i = 0; i < 16; i++) {
        const int r = i * 4 + tr;
        dst[(long)(c0 + r) * 768 + (r0 + tc)] = tile[tc * 65 + r];
    }
}

// ===========================================================================
// gemm256: 256x256-tile, BK=64, 8-wave, 8-phase deep-pipelined NT GEMM
// (m201 template: T1 xcd-swz + T2 LDS swizzle + T3/T4 counted vmcnt
//  + T5 setprio).  C[M,N] = A[M,K] * Bt[N,K]^T, bf16 in, fp32 acc.
//
// GRID IS 1-D. Hardware XCD = blockIdx.x % 8; swizzle chunks the full grid
// per-XCD. Decode is COLUMN-MAJOR (stationary-B): each XCD's contiguous
// chunk shares colf, so its B column-panel stays L2-resident while A
// streams. [R6 post-mortem: batch-per-XCD chunking put a 6MB Q+K working
// set on a 4MiB L2 -> thrash, top dispatch 90->103us. Column-panels are
// 0.4-3MB and fit. Do NOT chunk by batch.]
//
// K-loop structure is the R2-PROVEN form (conflicts 0). Do NOT re-add:
// lgkmcnt(N) pre-barrier throttles, hoisted 64-bit address lambdas (R3: -22%).
//
// MODE 1: C (fp32) = acc + bias[col] + resid[row*N+col]
// MODE 2: C (bf16) = acc / rowsum[bz*2048 + row]            (PV, normalize)
// MODE 3: C (bf16) = exp(acc*scale); atomicAdd row sums     (scores, fused softmax)
// MODE 4: QKV split: Cv=Qb base; sect=tile_n/768 routes to Q/K/V; qscale on Q
//         sect==2 (V) writes TRANSPOSED directly to Vt (passed via rowsum)
// ===========================================================================

// stage one 128x64 bf16 half-tile (16 KB): 2 x gload16 per thread.
// LDS dest linear; swizzle involution pre-applied to the GLOBAL source column.
__device__ __forceinline__ void stage_half256(const ushort_t* __restrict__ g, int row0,
                                              int Kd, int k0, ushort_t* l, int tid)
{
    #pragma unroll
    for (int i = 0; i < 2; i++) {
        const int c   = i * 512 + tid;          // 16B chunk index, 0..1023
        const int row = c >> 3;                 // 0..127
        const int scol = ((c & 7) ^ (row & 7)) * 8;  // src col, swizzle involution
        gload16(g + (long)(row0 + row) * Kd + (k0 + scol), l + c * 8);
    }
}

#define G256_BAR() do { \
    asm volatile("" ::: "memory"); \
    __builtin_amdgcn_s_barrier(); \
    asm volatile("" ::: "memory"); \
} while (0)

#define G256_LGKM0() asm volatile("s_waitcnt lgkmcnt(0)" ::: "memory")

#define G256_READ_A(q) do { \
    _Pragma("unroll") \
    for (int m2 = 0; m2 < 2; m2++) { \
        _Pragma("unroll") \
        for (int s = 0; s < 2; s++) { \
            int lb = (((q) * 2 + m2) * 16 + r16) * 128 + s * 64 + kq * 16; \
            lb ^= ((lb >> 7) & 7) << 4; \
            af[m2][s] = *reinterpret_cast<const bf16x8*>(LAc + (lb >> 1)); \
        } \
    } \
} while (0)

#define G256_MFMA(q) do { \
    __builtin_amdgcn_s_setprio(1); \
    _Pragma("unroll") \
    for (int m2 = 0; m2 < 2; m2++) { \
        _Pragma("unroll") \
        for (int ni = 0; ni < 4; ni++) { \
            acc[(q) * 2 + m2][ni] = __builtin_amdgcn_mfma_f32_16x16x32_bf16(af[m2][0], bg[ni][0], acc[(q) * 2 + m2][ni], 0, 0, 0); \
            acc[(q) * 2 + m2][ni] = __builtin_amdgcn_mfma_f32_16x16x32_bf16(af[m2][1], bg[ni][1], acc[(q) * 2 + m2][ni], 0, 0, 0); \
        } \
    } \
    __builtin_amdgcn_s_setprio(0); \
} while (0)

template<int MODE>
__global__ __launch_bounds__(512, 2)
void gemm256(const ushort_t* __restrict__ A, const ushort_t* __restrict__ Bt,
             void* __restrict__ Cv, int M, int N, int Kd,
             long batchA, long batchB, long batchC, float scale,
             const float* __restrict__ bias, const float* __restrict__ resid,
             float* __restrict__ rowsum)
{
    // [buf 0/1][A0,A1,B0,B1][128*64 bf16]  = 128 KiB
    __shared__ __align__(16) ushort_t lds[65536];

    // ---- XCD-aware swizzle over the FULL 1-D grid (hardware: x%8 -> XCD) ----
    const int nblk = gridDim.x;
    int lin = blockIdx.x;
    if ((nblk & 7) == 0) {
        const int per = nblk >> 3;
        lin = (lin & 7) * per + (lin >> 3);
    }
    const int ntN   = N >> 8;          // 256-tiles along N
    const int ntM   = M >> 8;          // 256-tiles along M
    const int nrows = nblk / ntN;      // = ntM * nbatch
    // column-major decode: per-XCD chunk shares colf -> stationary B-panel in L2
    const int colf = lin / nrows;
    const int rowf = lin - colf * nrows;
    const int bz   = rowf / ntM;       // batch (0 for nbatch=1 calls)
    const int tile_n = colf * 256;
    const int tile_m = (rowf % ntM) * 256;

    A  += (long)bz * batchA;
    Bt += (long)bz * batchB;

    const int tid  = threadIdx.x;
    const int w    = tid >> 6;
    const int lane = tid & 63;
    const int wr   = w >> 2;          // 0..1  (M-dim wave)
    const int wc   = w & 3;           // 0..3  (N-dim wave)
    const int r16  = lane & 15;
    const int kq   = lane >> 4;
    const int brow = (wc & 1) * 64;   // B row base within the wave's B-half

    const int NT = Kd >> 6;           // K-tiles of 64

    // element offsets: buf b base = b*32768; A0=+0 A1=+8192 B0=+16384 B1=+24576
    ushort_t* const sA = lds;
    ushort_t* const sB = lds + 16384;
    const ushort_t* const LA0 = lds + wr * 8192;
    const ushort_t* const LB0 = lds + 16384 + (wc >> 1) * 8192;

    f32x4 acc[8][4] = {};

    // ---- prologue: tile0 {A0,A1,B0,B1} + tile1 {B0,B1} ----
    stage_half256(A,  tile_m,       Kd, 0,  sA,         tid);
    stage_half256(A,  tile_m + 128, Kd, 0,  sA + 8192,  tid);
    stage_half256(Bt, tile_n,       Kd, 0,  sB,         tid);
    stage_half256(Bt, tile_n + 128, Kd, 0,  sB + 8192,  tid);
    if (NT > 1) {
        stage_half256(Bt, tile_n,       Kd, 64, sB + 32768,        tid);
        stage_half256(Bt, tile_n + 128, Kd, 64, sB + 32768 + 8192, tid);
        asm volatile("s_waitcnt vmcnt(4)" ::: "memory");   // tile0 landed
    } else {
        asm volatile("s_waitcnt vmcnt(0)" ::: "memory");
    }
    G256_BAR();

    int cur = 0;
    for (int t = 0; t < NT; ++t) {
        const int k0 = t << 6;
        const ushort_t* LAc = LA0 + cur * 32768;
        const ushort_t* LBc = LB0 + cur * 32768;
        ushort_t* const nA  = sA + (cur ^ 1) * 32768;   // tile t+1 A dest
        ushort_t* const nB  = sB + cur * 32768;         // tile t+2 B dest

        bf16x8 bg[4][2], af[2][2];

        // -------- phase 0: read all B frags + A quad 0; stage A-half0(t+1) --------
        #pragma unroll
        for (int ni = 0; ni < 4; ni++)
            #pragma unroll
            for (int s = 0; s < 2; s++) {
                int lb = (brow + ni * 16 + r16) * 128 + s * 64 + kq * 16;
                lb ^= ((lb >> 7) & 7) << 4;
                bg[ni][s] = *reinterpret_cast<const bf16x8*>(LBc + (lb >> 1));
            }
        G256_READ_A(0);
        if (t + 1 < NT) stage_half256(A, tile_m, Kd, k0 + 64, nA, tid);
        G256_BAR();
        G256_LGKM0();
        G256_MFMA(0);
        G256_BAR();

        // -------- phase 1: A quad 1; stage A-half1(t+1) --------
        G256_READ_A(1);
        if (t + 1 < NT) stage_half256(A, tile_m + 128, Kd, k0 + 64, nA + 8192, tid);
        G256_BAR();
        G256_LGKM0();
        G256_MFMA(1);
        G256_BAR();

        // -------- phase 2: A quad 2; stage B-half0(t+2) (B of tile t fully read) --------
        G256_READ_A(2);
        if (t + 2 < NT) stage_half256(Bt, tile_n, Kd, k0 + 128, nB, tid);
        G256_BAR();
        G256_LGKM0();
        G256_MFMA(2);
        G256_BAR();

        // -------- phase 3: A quad 3; stage B-half1(t+2); counted vmcnt --------
        G256_READ_A(3);
        if (t + 2 < NT) stage_half256(Bt, tile_n + 128, Kd, k0 + 128, nB + 8192, tid);
        G256_BAR();
        G256_LGKM0();
        G256_MFMA(3);
        if (t + 2 < NT) { asm volatile("s_waitcnt vmcnt(4)" ::: "memory"); }
        else            { asm volatile("s_waitcnt vmcnt(0)" ::: "memory"); }
        G256_BAR();
        cur ^= 1;
    }

    // ---- epilogues (C/D layout: col = lane&15, row = (lane>>4)*4 + reg) ----
    if (MODE == 1) {
        float* C = (float*)Cv;
        #pragma unroll
        for (int mi = 0; mi < 8; mi++)
            #pragma unroll
            for (int ni = 0; ni < 4; ni++)
                #pragma unroll
                for (int r = 0; r < 4; r++) {
                    const int row = tile_m + wr * 128 + mi * 16 + kq * 4 + r;
                    const int col = tile_n + wc * 64 + ni * 16 + r16;
                    C[(long)row * N + col] =
                        acc[mi][ni][r] + bias[col] + resid[(long)row * N + col];
                }
    } else if (MODE == 2) {
        ushort_t* C = (ushort_t*)Cv + (long)bz * batchC;
        const float* rs = rowsum + (long)bz * 2048;
        #pragma unroll
        for (int mi = 0; mi < 8; mi++) {
            float inv[4];
            #pragma unroll
            for (int r = 0; r < 4; r++)
                inv[r] = 1.0f / rs[tile_m + wr * 128 + mi * 16 + kq * 4 + r];
            #pragma unroll
            for (int ni = 0; ni < 4; ni++)
                #pragma unroll
                for (int r = 0; r < 4; r++) {
                    const int row = tile_m + wr * 128 + mi * 16 + kq * 4 + r;
                    const int col = tile_n + wc * 64 + ni * 16 + r16;
                    C[(long)row * N + col] = f2b(acc[mi][ni][r] * inv[r]);
                }
        }
    } else if (MODE == 3) {
        ushort_t* C = (ushort_t*)Cv + (long)bz * batchC;
        float* rs = rowsum + (long)bz * 2048;
        #pragma unroll
        for (int mi = 0; mi < 8; mi++)
            #pragma unroll
            for (int r = 0; r < 4; r++) {
                const int row = tile_m + wr * 128 + mi * 16 + kq * 4 + r;
                float psum = 0.f;
                #pragma unroll
                for (int ni = 0; ni < 4; ni++) {
                    const float e = __expf(acc[mi][ni][r] * scale);
                    psum += e;
                    const int col = tile_n + wc * 64 + ni * 16 + r16;
                    C[(long)row * N + col] = f2b(e);
                }
                psum += __shfl_xor(psum, 1);
                psum += __shfl_xor(psum, 2);
                psum += __shfl_xor(psum, 4);
                psum += __shfl_xor(psum, 8);
                if (r16 == 0) atomicAdd(&rs[row], psum);
            }
    } else {
        // MODE 4: fused QKV. Cv = Qb base; sections of MROWS*768 each.
        const int sect  = tile_n / 768;          // 256-tile lies in one section
        const int ncol0 = tile_n - sect * 768;
        if (sect == 2) {
            // V: write TRANSPOSED directly -> Vt[b][d][s]  (Vt passed via rowsum)
            ushort_t* Vt = (ushort_t*)rowsum;
            #pragma unroll
            for (int mi = 0; mi < 8; mi++)
                #pragma unroll
                for (int ni = 0; ni < 4; ni++) {
                    const int row = tile_m + wr * 128 + mi * 16 + kq * 4;
                    const int d   = ncol0 + wc * 64 + ni * 16 + r16;
                    const int b   = row >> 11, s = row & 2047;
                    ushort4 o;
                    o.x = f2b(acc[mi][ni][0]); o.y = f2b(acc[mi][ni][1]);
                    o.z = f2b(acc[mi][ni][2]); o.w = f2b(acc[mi][ni][3]);
                    *(ushort4*)(Vt + (long)b * ((long)2048 * 768) + (long)d * 2048 + s) = o;
                }
        } else {
            ushort_t* C = (ushort_t*)Cv + (size_t)sect * ((size_t)MROWS * 768);
            const float sc = (sect == 0) ? scale : 1.0f;
            #pragma unroll
            for (int mi = 0; mi < 8; mi++)
                #pragma unroll
                for (int ni = 0; ni < 4; ni++)
                    #pragma unroll
                    for (int r = 0; r < 4; r++) {
                        const int row = tile_m + wr * 128 + mi * 16 + kq * 4 + r;
                        const int col = ncol0 + wc * 64 + ni * 16 + r16;
                        C[(long)row * 768 + col] = f2b(acc[mi][ni][r] * sc);
                    }
        }
    }
}

// ---------------------------------------------------------------------------
// m97-structure 128^2 NT GEMM (kept for non-batched ws path)
// ---------------------------------------------------------------------------
template<int MODE>
__global__ __launch_bounds__(256)
void gemm_nt(const ushort_t* __restrict__ A, const ushort_t* __restrict__ Bt,
             void* __restrict__ Cv, int M, int N, int Kd,
             long batchA, long batchB, long batchC, float scale,
             const float* __restrict__ bias, const float* __restrict__ resid,
             float* __restrict__ rowsum)
{
    __shared__ __align__(16) ushort_t As[128 * 32];
    __shared__ __align__(16) ushort_t Bs[128 * 32];

    const int bz = blockIdx.z;
    A  += (long)bz * batchA;
    Bt += (long)bz * batchB;

    const int nxt  = gridDim.x;
    const int nblk = nxt * gridDim.y;
    int lin = blockIdx.y * nxt + blockIdx.x;
    if ((nblk & 7) == 0) {
        const int per = nblk >> 3;
        lin = (lin & 7) * per + (lin >> 3);
    }
    const int tile_n = (lin % nxt) * 128;
    const int tile_m = (lin / nxt) * 128;

    const int tid  = threadIdx.x;
    const int w    = tid >> 6;
    const int lane = tid & 63;
    const int wr = w >> 1, wc = w & 1;
    const int r16 = lane & 15;
    const int kq  = lane >> 4;

    const int srow   = lane >> 2;
    const int schunk = lane & 3;
    const int arow0 = w * 32 + srow;
    const int arow1 = arow0 + 16;
    const int g0 = (schunk ^ ((arow0 >> 1) & 3)) * 8;
    const int g1 = (schunk ^ ((arow1 >> 1) & 3)) * 8;

    const ushort_t* Ar0 = A  + (long)(tile_m + arow0) * Kd + g0;
    const ushort_t* Ar1 = A  + (long)(tile_m + arow1) * Kd + g1;
    const ushort_t* Br0 = Bt + (long)(tile_n + arow0) * Kd + g0;
    const ushort_t* Br1 = Bt + (long)(tile_n + arow1) * Kd + g1;

    ushort_t* lA0 = &As[(w * 32     ) * 32];
    ushort_t* lA1 = &As[(w * 32 + 16) * 32];
    ushort_t* lB0 = &Bs[(w * 32     ) * 32];
    ushort_t* lB1 = &Bs[(w * 32 + 16) * 32];

    f32x4 acc[4][4] = {};

    for (int k0 = 0; k0 < Kd; k0 += 32) {
        gload16(Ar0 + k0, lA0);
        gload16(Ar1 + k0, lA1);
        gload16(Br0 + k0, lB0);
        gload16(Br1 + k0, lB1);
        __syncthreads();

        bf16x8 af[4], bg[4];
        #pragma unroll
        for (int i = 0; i < 4; i++) {
            const int ra = wr * 64 + i * 16 + r16;
            af[i] = *reinterpret_cast<const bf16x8*>(&As[ra * 32 + ((kq ^ ((ra >> 1) & 3)) * 8)]);
            const int rb = wc * 64 + i * 16 + r16;
            bg[i] = *reinterpret_cast<const bf16x8*>(&Bs[rb * 32 + ((kq ^ ((rb >> 1) & 3)) * 8)]);
        }
        #pragma unroll
        for (int mi = 0; mi < 4; mi++)
            #pragma unroll
            for (int ni = 0; ni < 4; ni++)
                acc[mi][ni] = __builtin_amdgcn_mfma_f32_16x16x32_bf16(af[mi], bg[ni], acc[mi][ni], 0, 0, 0);
        __syncthreads();
    }

    if (MODE == 0) {
        ushort_t* C = (ushort_t*)Cv + (long)bz * batchC;
        #pragma unroll
        for (int mi = 0; mi < 4; mi++)
            #pragma unroll
            for (int ni = 0; ni < 4; ni++)
                #pragma unroll
                for (int r = 0; r < 4; r++) {
                    const int row = tile_m + wr * 64 + mi * 16 + kq * 4 + r;
                    const int col = tile_n + wc * 64 + ni * 16 + r16;
                    C[(long)row * N + col] = f2b(acc[mi][ni][r] * scale);
                }
    } else if (MODE == 1) {
        float* C = (float*)Cv;
        #pragma unroll
        for (int mi = 0; mi < 4; mi++)
            #pragma unroll
            for (int ni = 0; ni < 4; ni++)
                #pragma unroll
                for (int r = 0; r < 4; r++) {
                    const int row = tile_m + wr * 64 + mi * 16 + kq * 4 + r;
                    const int col = tile_n + wc * 64 + ni * 16 + r16;
                    C[(long)row * N + col] =
                        acc[mi][ni][r] + bias[col] + resid[(long)row * N + col];
                }
    } else if (MODE == 2) {
        ushort_t* C = (ushort_t*)Cv + (long)bz * batchC;
        const float* rs = rowsum + (long)bz * 2048;
        #pragma unroll
        for (int mi = 0; mi < 4; mi++) {
            float inv[4];
            #pragma unroll
            for (int r = 0; r < 4; r++)
                inv[r] = 1.0f / rs[tile_m + wr * 64 + mi * 16 + kq * 4 + r];
            #pragma unroll
            for (int ni = 0; ni < 4; ni++)
                #pragma unroll
                for (int r = 0; r < 4; r++) {
                    const int row = tile_m + wr * 64 + mi * 16 + kq * 4 + r;
                    const int col = tile_n + wc * 64 + ni * 16 + r16;
                    C[(long)row * N + col] = f2b(acc[mi][ni][r] * inv[r]);
                }
        }
    } else if (MODE == 3) {
        ushort_t* C = (ushort_t*)Cv + (long)bz * batchC;
        float* rs = rowsum + (long)bz * 2048;
        #pragma unroll
        for (int mi = 0; mi < 4; mi++)
            #pragma unroll
            for (int r = 0; r < 4; r++) {
                const int row = tile_m + wr * 64 + mi * 16 + kq * 4 + r;
                float psum = 0.f;
                #pragma unroll
                for (int ni = 0; ni < 4; ni++) {
                    const float e = __expf(acc[mi][ni][r] * scale);
                    psum += e;
                    const int col = tile_n + wc * 64 + ni * 16 + r16;
                    C[(long)row * N + col] = f2b(e);
                }
                psum += __shfl_xor(psum, 1);
                psum += __shfl_xor(psum, 2);
                psum += __shfl_xor(psum, 4);
                psum += __shfl_xor(psum, 8);
                if (r16 == 0) atomicAdd(&rs[row], psum);
            }
    } else {
        const int sect  = tile_n / 768;
        const int ncol0 = tile_n - sect * 768;
        ushort_t* C = (ushort_t*)Cv + (size_t)sect * ((size_t)MROWS * 768);
        const float sc = (sect == 0) ? scale : 1.0f;
        #pragma unroll
        for (int mi = 0; mi < 4; mi++)
            #pragma unroll
            for (int ni = 0; ni < 4; ni++)
                #pragma unroll
                for (int r = 0; r < 4; r++) {
                    const int row = tile_m + wr * 64 + mi * 16 + kq * 4 + r;
                    const int col = ncol0 + wc * 64 + ni * 16 + r16;
                    C[(long)row * 768 + col] = f2b(acc[mi][ni][r] * sc);
                }
    }
}

// ---------------------------------------------------------------------------
// Fallback GEMM (round-3 proven) — only if ws too small for fast paths
// ---------------------------------------------------------------------------
template<int TRANSB, int MODE, int BF32>
__global__ __launch_bounds__(256)
void gemm_s(const ushort_t* __restrict__ A, const void* __restrict__ Bsrc,
            void* __restrict__ Cv, int M, int N, int Kd, float scale,
            const float* __restrict__ bias, const float* __restrict__ resid)
{
    __shared__ __align__(16) ushort_t As[128 * LDST];
    __shared__ __align__(16) ushort_t Bs[128 * LDST];
    const int tile_n = blockIdx.x * 128;
    const int tile_m = blockIdx.y * 128;
    const int tid  = threadIdx.x;
    const int w    = tid >> 6;
    const int lane = tid & 63;
    const int wr = w >> 1, wc = w & 1;
    const int r16 = lane & 15;
    const int kq  = lane >> 4;
    f32x4 acc[4][4] = {};
    for (int k0 = 0; k0 < Kd; k0 += 32) {
        #pragma unroll
        for (int cc = 0; cc < 2; cc++) {
            const int c = tid + cc * 256;
            const int row = c >> 2, col = (c & 3) * 8;
            *(uint4*)&As[row * LDST + col] = *(const uint4*)(A + (long)(tile_m + row) * Kd + k0 + col);
        }
        if (TRANSB == 0) {
            const ushort_t* Bt = (const ushort_t*)Bsrc;
            #pragma unroll
            for (int cc = 0; cc < 2; cc++) {
                const int c = tid + cc * 256;
                const int row = c >> 2, col = (c & 3) * 8;
                *(uint4*)&Bs[row * LDST + col] = *(const uint4*)(Bt + (long)(tile_n + row) * Kd + k0 + col);
            }
        } else {
            #pragma unroll
            for (int i = 0; i < 16; i++) {
                const int lin = i * 256 + tid;
                const int kr = lin >> 7, nc = lin & 127;
                ushort_t bv;
                if (BF32) bv = f2b(((const float*)Bsrc)[(long)(k0 + kr) * N + tile_n + nc]);
                else      bv = ((const ushort_t*)Bsrc)[(long)(k0 + kr) * N + tile_n + nc];
                Bs[nc * LDST + kr] = bv;
            }
        }
        __syncthreads();
        bf16x8 af[4], bg[4];
        #pragma unroll
        for (int i = 0; i < 4; i++) {
            af[i] = *reinterpret_cast<const bf16x8*>(&As[(wr * 64 + i * 16 + r16) * LDST + kq * 8]);
            bg[i] = *reinterpret_cast<const bf16x8*>(&Bs[(wc * 64 + i * 16 + r16) * LDST + kq * 8]);
        }
        #pragma unroll
        for (int mi = 0; mi < 4; mi++)
            #pragma unroll
            for (int ni = 0; ni < 4; ni++)
                acc[mi][ni] = __builtin_amdgcn_mfma_f32_16x16x32_bf16(af[mi], bg[ni], acc[mi][ni], 0, 0, 0);
        __syncthreads();
    }
    if (MODE == 0) {
        ushort_t* C = (ushort_t*)Cv;
        #pragma unroll
        for (int mi = 0; mi < 4; mi++)
            #pragma unroll
            for (int ni = 0; ni < 4; ni++)
                #pragma unroll
                for (int r = 0; r < 4; r++) {
                    const int row = tile_m + wr * 64 + mi * 16 + kq * 4 + r;
                    const int col = tile_n + wc * 64 + ni * 16 + r16;
                    C[(long)row * N + col] = f2b(acc[mi][ni][r] * scale);
                }
    } else {
        float* C = (float*)Cv;
        #pragma unroll
        for (int mi = 0; mi < 4; mi++)
            #pragma unroll
            for (int ni = 0; ni < 4; ni++)
                #pragma unroll
                for (int r = 0; r < 4; r++) {
                    const int row = tile_m + wr * 64 + mi * 16 + kq * 4 + r;
                    const int col = tile_n + wc * 64 + ni * 16 + r16;
                    C[(long)row * N + col] =
                        acc[mi][ni][r] + bias[col] + resid[(long)row * N + col];
                }
    }
}

// softmax over rows of 2048 bf16 (fallback path only)
__global__ void softmax_rows(ushort_t* __restrict__ p)
{
    __shared__ float sm[4], ss_[4];
    ushort_t* pr = p + (long)blockIdx.x * 2048;
    const int tid = threadIdx.x;
    const int w = tid >> 6;
    const uint4 raw = *(const uint4*)(pr + tid * 8);
    float v[8];
    v[0] = b2f((ushort_t)(raw.x & 0xffff)); v[1] = b2f((ushort_t)(raw.x >> 16));
    v[2] = b2f((ushort_t)(raw.y & 0xffff)); v[3] = b2f((ushort_t)(raw.y >> 16));
    v[4] = b2f((ushort_t)(raw.z & 0xffff)); v[5] = b2f((ushort_t)(raw.z >> 16));
    v[6] = b2f((ushort_t)(raw.w & 0xffff)); v[7] = b2f((ushort_t)(raw.w >> 16));
    float mx = -3.0e38f;
    #pragma unroll
    for (int i = 0; i < 8; i++) mx = fmaxf(mx, v[i]);
    #pragma unroll
    for (int off = 32; off; off >>= 1) mx = fmaxf(mx, __shfl_xor(mx, off));
    if ((tid & 63) == 0) sm[w] = mx;
    __syncthreads();
    mx = fmaxf(fmaxf(sm[0], sm[1]), fmaxf(sm[2], sm[3]));
    float s = 0.f;
    #pragma unroll
    for (int i = 0; i < 8; i++) { v[i] = __expf(v[i] - mx); s += v[i]; }
    #pragma unroll
    for (int off = 32; off; off >>= 1) s += __shfl_xor(s, off);
    if ((tid & 63) == 0) ss_[w] = s;
    __syncthreads();
    s = ss_[0] + ss_[1] + ss_[2] + ss_[3];
    const float inv = 1.f / s;
    uint4 o;
    o.x = f2b(v[0] * inv) | ((unsigned)f2b(v[1] * inv) << 16);
    o.y = f2b(v[2] * inv) | ((unsigned)f2b(v[3] * inv) << 16);
    o.z = f2b(v[4] * inv) | ((unsigned)f2b(v[5] * inv) << 16);
    o.w = f2b(v[6] * inv) | ((unsigned)f2b(v[7] * inv) << 16);
    *(uint4*)(pr + tid * 8) = o;
}

// double layernorm per fp32 row of 768, IN PLACE
__global__ void ln_fused(float* __restrict__ x,
                         const float* __restrict__ w1, const float* __restrict__ b1,
                         const float* __restrict__ w2, const float* __restrict__ b2)
{
    __shared__ float r1s[4], r1q[4], r2s[4], r2q[4];
    const long row = blockIdx.x;
    const int tid = threadIdx.x;
    const int w = tid >> 6;
    float* xr = x + row * 768;
    float v[3], s = 0.f, q = 0.f;
    #pragma unroll
    for (int i = 0; i < 3; i++) { const float t = xr[tid + i * 256]; v[i] = t; s += t; q += t * t; }
    #pragma unroll
    for (int off = 32; off; off >>= 1) { s += __shfl_xor(s, off); q += __shfl_xor(q, off); }
    if ((tid & 63) == 0) { r1s[w] = s; r1q[w] = q; }
    __syncthreads();
    s = r1s[0] + r1s[1] + r1s[2] + r1s[3];
    q = r1q[0] + r1q[1] + r1q[2] + r1q[3];
    float mu = s * (1.f / 768.f);
    float ri = rsqrtf(q * (1.f / 768.f) - mu * mu + EPS);
    float y[3];
    s = 0.f; q = 0.f;
    #pragma unroll
    for (int i = 0; i < 3; i++) {
        const int d = tid + i * 256;
        const float t = (v[i] - mu) * ri * w1[d] + b1[d];
        y[i] = t; s += t; q += t * t;
    }
    #pragma unroll
    for (int off = 32; off; off >>= 1) { s += __shfl_xor(s, off); q += __shfl_xor(q, off); }
    if ((tid & 63) == 0) { r2s[w] = s; r2q[w] = q; }
    __syncthreads();
    s = r2s[0] + r2s[1] + r2s[2] + r2s[3];
    q = r2q[0] + r2q[1] + r2q[2] + r2q[3];
    mu = s * (1.f / 768.f);
    ri = rsqrtf(q * (1.f / 768.f) - mu * mu + EPS);
    #pragma unroll
    for (int i = 0; i < 3; i++) {
        const int d = tid + i * 256;
        xr[d] = (y[i] - mu) * ri * w2[d] + b2[d];
    }
}

__global__ void pool_reduce(const float* __restrict__ x, float* __restrict__ pooled)
{
    const int d  = blockIdx.x * 256 + threadIdx.x;
    const int b  = blockIdx.z;
    const int sp = blockIdx.y;
    const float* base = x + ((long)b * 2048 + sp * 128) * 768 + d;
    float s = 0.f;
    #pragma unroll 8
    for (int i = 0; i < 128; i++) s += base[(long)i * 768];
    atomicAdd(&pooled[b * 768 + d], s);
}

// 80 blocks x 64 lanes: one wave per (b, o)
__global__ void logits_kernel(const float* __restrict__ pooled, const float* __restrict__ Wc,
                              const float* __restrict__ bc, float* __restrict__ out)
{
    const int b = blockIdx.x / 10, o = blockIdx.x % 10;
    const int lane = threadIdx.x;
    float s = 0.f;
    #pragma unroll
    for (int d = lane; d < 768; d += 64) s += pooled[b * 768 + d] * Wc[d * 10 + o];
    #pragma unroll
    for (int off = 32; off; off >>= 1) s += __shfl_xor(s, off);
    if (lane == 0) out[b * 10 + o] = s * (1.f / 2048.f) + bc[o];
}

extern "C" void kernel_launch(void* const* d_in, const int* in_sizes, int n_in,
                              void* d_out, int out_size, void* d_ws, size_t ws_size,
                              hipStream_t stream)
{
    (void)in_sizes; (void)n_in; (void)out_size;
    const float* src  = (const float*)d_in[0];
    const float* Wq   = (const float*)d_in[1];
    const float* Wk   = (const float*)d_in[2];
    const float* Wv   = (const float*)d_in[3];
    const float* Wo   = (const float*)d_in[4];
    const float* bo   = (const float*)d_in[5];
    const float* ln1w = (const float*)d_in[6];
    const float* ln1b = (const float*)d_in[7];
    const float* ln2w = (const float*)d_in[8];
    const float* ln2b = (const float*)d_in[9];
    const float* Wc   = (const float*)d_in[10];
    const float* bc   = (const float*)d_in[11];
    float* out = (float*)d_out;

    const dim3 blk(256);
    const dim3 blk512(512);
    const float qscale = 1.0f / sqrtf(768.0f);
    const long bs = (long)2048 * 768;

    const size_t WT    = (size_t)768 * 768 * 2;          // 256-mult: Wt bufs contiguous
    const size_t BUF   = (size_t)MROWS * 768 * 2;        // 256-mult: Q/K/V contiguous
    const size_t POOLB = 24576;
    const size_t RSB   = (size_t)B_ * 2048 * 4;          // rowsum, 64 KB
    const size_t PROBS8 = (size_t)8 * 2048 * 2048 * 2;
    const size_t needB = 4 * WT + 5 * BUF + POOLB + RSB;  // ~130.7 MB
    const size_t needA = needB + PROBS8;                  // ~197.8 MB

    char* ws = (char*)d_ws;
    size_t off = 0;
    auto alloc = [&](size_t bytes) { void* p = ws + off; off += (bytes + 255) & ~(size_t)255; return p; };

    if (ws_size >= needB) {
        ushort_t* Wtq  = (ushort_t*)alloc(WT);   // Wtq/Wtk/Wtv contiguous => fused QKV B operand
        ushort_t* Wtk  = (ushort_t*)alloc(WT);
        ushort_t* Wtv  = (ushort_t*)alloc(WT);
        ushort_t* Wto  = (ushort_t*)alloc(WT);
        ushort_t* srcb = (ushort_t*)alloc(BUF);
        ushort_t* Qb   = (ushort_t*)alloc(BUF);  // Qb/Kb/Vb contiguous => MODE 4 sect routing
        ushort_t* Kb   = (ushort_t*)alloc(BUF);
        ushort_t* Vb   = (ushort_t*)alloc(BUF);  // untouched by QKV (V goes to Vt); reused as attn
        ushort_t* Vt   = (ushort_t*)alloc(BUF);  // written DIRECTLY by QKV epilogue (transposed)
        float*  pooled = (float*)  alloc(POOLB);
        float*  rowsum = (float*)  alloc(RSB);
        const bool batched = (ws_size >= needA);
        ushort_t* probs = batched ? (ushort_t*)alloc(PROBS8) : srcb;  // srcb dead after QKV
        ushort_t* attn  = Vb;
        float*    xpre  = out + 80;
        (void)Wtk; (void)Wtv;

        cast_f32_bf16<<<MROWS * 768 / 1024, blk, 0, stream>>>(src, srcb, (long)MROWS * 768);
        transpose_w4<<<dim3(12, 12, 4), blk, 0, stream>>>(Wq, Wk, Wv, Wo, Wtq);

        // fused QKV: [16384,768] @ [2304,768]^T; Q/K -> Qb/Kb, V -> Vt (transposed in epilogue)
        gemm256<4><<<dim3(576), blk512, 0, stream>>>(srcb, Wtq, Qb, MROWS, 2304, 768,
                                                     0, 0, 0, qscale, nullptr, nullptr, (float*)Vt);

        hipMemsetAsync(rowsum, 0, RSB, stream);

        if (batched) {
            // scores: exp(QK^T) with fused row-sum atomics; stationary-B chunking
            gemm256<3><<<dim3(512), blk512, 0, stream>>>(Qb, Kb, probs, 2048, 2048, 768,
                                                         bs, bs, (long)2048 * 2048, 1.0f,
                                                         nullptr, nullptr, rowsum);
            // PV: normalize by rowsum in epilogue; stationary-B chunking
            gemm256<2><<<dim3(192), blk512, 0, stream>>>(probs, Vt, attn, 2048, 768, 2048,
                                                         (long)2048 * 2048, bs, bs, 1.0f,
                                                         nullptr, nullptr, rowsum);
        } else {
            for (int bz = 0; bz < B_; bz += 2) {
                gemm_nt<3><<<dim3(16, 16, 2), blk, 0, stream>>>(Qb + bz * bs, Kb + bz * bs, probs,
                                                                2048, 2048, 768, bs, bs, (long)2048 * 2048,
                                                                1.0f, nullptr, nullptr, rowsum + bz * 2048);
                gemm_nt<2><<<dim3(6, 16, 2), blk, 0, stream>>>(probs, Vt + bz * bs, attn + bz * bs,
                                                               2048, 768, 2048,
                                                               (long)2048 * 2048, bs, bs, 1.0f,
                                                               nullptr, nullptr, rowsum + bz * 2048);
            }
        }

        gemm256<1><<<dim3(192), blk512, 0, stream>>>(attn, Wto, xpre, MROWS, 768, 768,
                                                     0, 0, 0, 1.0f, bo, src, nullptr);
        ln_fused<<<MROWS, blk, 0, stream>>>(xpre, ln1w, ln1b, ln2w, ln2b);
        hipMemsetAsync(pooled, 0, B_ * 768 * 4, stream);
        pool_reduce<<<dim3(3, 16, B_), blk, 0, stream>>>(xpre, pooled);
        logits_kernel<<<80, 64, 0, stream>>>(pooled, Wc, bc, out);
    } else {
        // round-3 proven fallback (~100.7 MB)
        ushort_t* srcb = (ushort_t*)alloc(BUF);
        ushort_t* Qb   = (ushort_t*)alloc(BUF);
        ushort_t* Kb   = (ushort_t*)alloc(BUF);
        ushort_t* Vb   = (ushort_t*)alloc(BUF);
        float*  pooled = (float*)  alloc(POOLB);
        ushort_t* probs = srcb;
        ushort_t* attn  = Qb;
        float*    xpre  = out + 80;

        cast_f32_bf16<<<MROWS * 768 / 1024, blk, 0, stream>>>(src, srcb, (long)MROWS * 768);
        gemm_s<1, 0, 1><<<dim3(6, 128), blk, 0, stream>>>(srcb, Wq, Qb, MROWS, 768, 768, qscale, nullptr, nullptr);
        gemm_s<1, 0, 1><<<dim3(6, 128), blk, 0, stream>>>(srcb, Wk, Kb, MROWS, 768, 768, 1.0f, nullptr, nullptr);
        gemm_s<1, 0, 1><<<dim3(6, 128), blk, 0, stream>>>(srcb, Wv, Vb, MROWS, 768, 768, 1.0f, nullptr, nullptr);
        for (int bz = 0; bz < B_; bz++) {
            gemm_s<0, 0, 0><<<dim3(16, 16), blk, 0, stream>>>(Qb + bz * bs, Kb + bz * bs, probs,
                                                              2048, 2048, 768, 1.0f, nullptr, nullptr);
            softmax_rows<<<2048, blk, 0, stream>>>(probs);
            gemm_s<1, 0, 0><<<dim3(6, 16), blk, 0, stream>>>(probs, Vb + bz * bs, attn + bz * bs,
                                                             2048, 768, 2048, 1.0f, nullptr, nullptr);
        }
        gemm_s<1, 1, 1><<<dim3(6, 128), blk, 0, stream>>>(attn, Wo, xpre, MROWS, 768, 768, 1.0f, bo, src);
        ln_fused<<<MROWS, blk, 0, stream>>>(xpre, ln1w, ln1b, ln2w, ln2b);
        hipMemsetAsync(pooled, 0, B_ * 768 * 4, stream);
        pool_reduce<<<dim3(3, 16, B_), blk, 0, stream>>>(xpre, pooled);
        logits_kernel<<<80, 64, 0, stream>>>(pooled, Wc, bc, out);
    }
}

// Round 8
// 423.283 us; speedup vs baseline: 1.0241x; 1.0241x over previous
//
#include <hip/hip_runtime.h>
#include <cmath>

typedef unsigned short ushort_t;
typedef __bf16 bf16x8 __attribute__((ext_vector_type(8)));
typedef float  f32x4  __attribute__((ext_vector_type(4)));

#define B_  8
#define S_  2048
#define D_  768
#define MROWS (B_ * S_)       // 16384
#define EPS 1e-5f
#define LDST 40               // padded stride for fallback gemm only

__device__ __forceinline__ float b2f(ushort_t u) {
    union { unsigned int i; float f; } v; v.i = ((unsigned int)u) << 16; return v.f;
}
__device__ __forceinline__ ushort_t f2b(float f) {
    union { float f; unsigned int i; } v; v.f = f;
    unsigned int r = v.i + 0x7fffu + ((v.i >> 16) & 1u);
    return (ushort_t)(r >> 16);
}

// async 16B global->LDS; LDS dest = wave-uniform base + lane*16
__device__ __forceinline__ void gload16(const ushort_t* g, ushort_t* l) {
    __builtin_amdgcn_global_load_lds((__attribute__((address_space(1))) void*)g,
                                     (__attribute__((address_space(3))) void*)l,
                                     16, 0, 0);
}

// fp32 -> bf16 cast, 4 elems/thread
__global__ void cast_f32_bf16(const float* __restrict__ in, ushort_t* __restrict__ outp, long n)
{
    const long i = ((long)blockIdx.x * 256 + threadIdx.x) * 4;
    if (i + 3 < n) {
        const float4 v = *(const float4*)(in + i);
        ushort4 o;
        o.x = f2b(v.x); o.y = f2b(v.y); o.z = f2b(v.z); o.w = f2b(v.w);
        *(ushort4*)(outp + i) = o;
    }
}

// ---------------------------------------------------------------------------
// transpose (+optional fp32->bf16 cast): dst[C][R] = cvt(src[R][C]), z-batched
// (kept for fallback path)
// ---------------------------------------------------------------------------
template<int F32IN>
__global__ void transpose_any(const void* __restrict__ srcv, ushort_t* __restrict__ dst,
                              int R, int C, long sb, long db)
{
    __shared__ ushort_t tile[64 * 65];
    dst += (long)blockIdx.z * db;
    const int r0 = blockIdx.y * 64, c0 = blockIdx.x * 64;
    const int t = threadIdx.x;
    const int tr = t >> 6, tc = t & 63;
    #pragma unroll
    for (int i = 0; i < 16; i++) {
        const int r = i * 4 + tr;
        ushort_t v;
        if (F32IN) v = f2b(((const float*)srcv + (long)blockIdx.z * sb)[(long)(r0 + r) * C + (c0 + tc)]);
        else       v = ((const ushort_t*)srcv + (long)blockIdx.z * sb)[(long)(r0 + r) * C + (c0 + tc)];
        tile[r * 65 + tc] = v;
    }
    __syncthreads();
    #pragma unroll
    for (int i = 0; i < 16; i++) {
        const int r = i * 4 + tr;
        dst[(long)(c0 + r) * R + (r0 + tc)] = tile[tc * 65 + r];
    }
}

// all four 768x768 weight transposes in ONE dispatch (z selects the weight;
// dst buffers are contiguous at stride 768*768)
__global__ void transpose_w4(const float* __restrict__ w0, const float* __restrict__ w1,
                             const float* __restrict__ w2, const float* __restrict__ w3,
                             ushort_t* __restrict__ dst)
{
    __shared__ ushort_t tile[64 * 65];
    const float* src = (blockIdx.z == 0) ? w0 : (blockIdx.z == 1) ? w1
                     : (blockIdx.z == 2) ? w2 : w3;
    dst += (size_t)blockIdx.z * ((size_t)768 * 768);
    const int r0 = blockIdx.y * 64, c0 = blockIdx.x * 64;
    const int t = threadIdx.x;
    const int tr = t >> 6, tc = t & 63;
    #pragma unroll
    for (int i = 0; i < 16; i++) {
        const int r = i * 4 + tr;
        tile[r * 65 + tc] = f2b(src[(long)(r0 + r) * 768 + (c0 + tc)]);
    }
    __syncthreads();
    #pragma unroll
    for (int i = 0; i < 16; i++) {
        const int r = i * 4 + tr;
        dst[(long)(c0 + r) * 768 + (r0 + tc)] = tile[tc * 65 + r];
    }
}

// ===========================================================================
// gemm256: 256x256-tile, BK=64, 8-wave, 8-phase deep-pipelined NT GEMM
// (m201 template: T1 xcd-swz + T2 LDS swizzle + T3/T4 counted vmcnt
//  + T5 setprio).  C[M,N] = A[M,K] * Bt[N,K]^T, bf16 in, fp32 acc.
//
// GRID IS 1-D. Hardware XCD = blockIdx.x % 8; swizzle chunks the full grid
// per-XCD. Decode: rowf-dims ordered (tile_m OUTER, bz INNER):
//   - tile_m derives from the chunk index -> each XCD keeps ONE A row-panel
//     (768KB) L2-stationary and is the SOLE reader of its A panels (A fetched
//     from HBM exactly once overall);
//   - (bz, colf) derive from the within-chunk index -> all 8 XCDs sweep the
//     SAME B-tile co-temporally, so B is HBM-fetched once and L3-served.
// [R7 post-mortem: column-major chunking made every XCD read ALL of A ->
//  FETCH doubled (55->116MB). R6 batch-chunking broke B co-temporality.
//  This decode reproduces R5's measured-best scores pattern (90us, 55MB)
//  while keeping nb=1 dispatches (QKV/Wo) identical to R6's best.]
//
// K-loop structure is the R2-PROVEN form (conflicts 0). Do NOT re-add:
// lgkmcnt(N) pre-barrier throttles, hoisted 64-bit address lambdas (R3: -22%).
//
// MODE 1: C (fp32) = acc + bias[col] + resid[row*N+col]
// MODE 2: C (bf16) = acc / rowsum[bz*2048 + row]            (PV, normalize)
// MODE 3: C (bf16) = exp(acc*scale); atomicAdd row sums     (scores, fused softmax)
// MODE 4: QKV split: Cv=Qb base; sect=tile_n/768 routes to Q/K/V; qscale on Q
//         sect==2 (V) writes TRANSPOSED directly to Vt (passed via rowsum)
// ===========================================================================

// stage one 128x64 bf16 half-tile (16 KB): 2 x gload16 per thread.
// LDS dest linear; swizzle involution pre-applied to the GLOBAL source column.
__device__ __forceinline__ void stage_half256(const ushort_t* __restrict__ g, int row0,
                                              int Kd, int k0, ushort_t* l, int tid)
{
    #pragma unroll
    for (int i = 0; i < 2; i++) {
        const int c   = i * 512 + tid;          // 16B chunk index, 0..1023
        const int row = c >> 3;                 // 0..127
        const int scol = ((c & 7) ^ (row & 7)) * 8;  // src col, swizzle involution
        gload16(g + (long)(row0 + row) * Kd + (k0 + scol), l + c * 8);
    }
}

#define G256_BAR() do { \
    asm volatile("" ::: "memory"); \
    __builtin_amdgcn_s_barrier(); \
    asm volatile("" ::: "memory"); \
} while (0)

#define G256_LGKM0() asm volatile("s_waitcnt lgkmcnt(0)" ::: "memory")

#define G256_READ_A(q) do { \
    _Pragma("unroll") \
    for (int m2 = 0; m2 < 2; m2++) { \
        _Pragma("unroll") \
        for (int s = 0; s < 2; s++) { \
            int lb = (((q) * 2 + m2) * 16 + r16) * 128 + s * 64 + kq * 16; \
            lb ^= ((lb >> 7) & 7) << 4; \
            af[m2][s] = *reinterpret_cast<const bf16x8*>(LAc + (lb >> 1)); \
        } \
    } \
} while (0)

#define G256_MFMA(q) do { \
    __builtin_amdgcn_s_setprio(1); \
    _Pragma("unroll") \
    for (int m2 = 0; m2 < 2; m2++) { \
        _Pragma("unroll") \
        for (int ni = 0; ni < 4; ni++) { \
            acc[(q) * 2 + m2][ni] = __builtin_amdgcn_mfma_f32_16x16x32_bf16(af[m2][0], bg[ni][0], acc[(q) * 2 + m2][ni], 0, 0, 0); \
            acc[(q) * 2 + m2][ni] = __builtin_amdgcn_mfma_f32_16x16x32_bf16(af[m2][1], bg[ni][1], acc[(q) * 2 + m2][ni], 0, 0, 0); \
        } \
    } \
    __builtin_amdgcn_s_setprio(0); \
} while (0)

template<int MODE>
__global__ __launch_bounds__(512, 2)
void gemm256(const ushort_t* __restrict__ A, const ushort_t* __restrict__ Bt,
             void* __restrict__ Cv, int M, int N, int Kd,
             long batchA, long batchB, long batchC, float scale,
             const float* __restrict__ bias, const float* __restrict__ resid,
             float* __restrict__ rowsum)
{
    // [buf 0/1][A0,A1,B0,B1][128*64 bf16]  = 128 KiB
    __shared__ __align__(16) ushort_t lds[65536];

    // ---- XCD-aware swizzle over the FULL 1-D grid (hardware: x%8 -> XCD) ----
    const int nblk = gridDim.x;
    int lin = blockIdx.x;
    if ((nblk & 7) == 0) {
        const int per = nblk >> 3;
        lin = (lin & 7) * per + (lin >> 3);
    }
    const int ntN   = N >> 8;          // 256-tiles along N
    const int ntM   = M >> 8;          // 256-tiles along M
    const int nrows = nblk / ntN;      // = ntM * nbatch
    const int nb    = nrows / ntM;     // batch count
    const int colf = lin % ntN;
    const int rowf = lin / ntN;
    // batch-INNER decode: tile_m from chunk (stationary A-panel per XCD),
    // (bz, colf) from within-chunk index (co-temporal B across XCDs)
    const int bz     = rowf % nb;
    const int tile_m = (rowf / nb) * 256;
    const int tile_n = colf * 256;

    A  += (long)bz * batchA;
    Bt += (long)bz * batchB;

    const int tid  = threadIdx.x;
    const int w    = tid >> 6;
    const int lane = tid & 63;
    const int wr   = w >> 2;          // 0..1  (M-dim wave)
    const int wc   = w & 3;           // 0..3  (N-dim wave)
    const int r16  = lane & 15;
    const int kq   = lane >> 4;
    const int brow = (wc & 1) * 64;   // B row base within the wave's B-half

    const int NT = Kd >> 6;           // K-tiles of 64

    // element offsets: buf b base = b*32768; A0=+0 A1=+8192 B0=+16384 B1=+24576
    ushort_t* const sA = lds;
    ushort_t* const sB = lds + 16384;
    const ushort_t* const LA0 = lds + wr * 8192;
    const ushort_t* const LB0 = lds + 16384 + (wc >> 1) * 8192;

    f32x4 acc[8][4] = {};

    // ---- prologue: tile0 {A0,A1,B0,B1} + tile1 {B0,B1} ----
    stage_half256(A,  tile_m,       Kd, 0,  sA,         tid);
    stage_half256(A,  tile_m + 128, Kd, 0,  sA + 8192,  tid);
    stage_half256(Bt, tile_n,       Kd, 0,  sB,         tid);
    stage_half256(Bt, tile_n + 128, Kd, 0,  sB + 8192,  tid);
    if (NT > 1) {
        stage_half256(Bt, tile_n,       Kd, 64, sB + 32768,        tid);
        stage_half256(Bt, tile_n + 128, Kd, 64, sB + 32768 + 8192, tid);
        asm volatile("s_waitcnt vmcnt(4)" ::: "memory");   // tile0 landed
    } else {
        asm volatile("s_waitcnt vmcnt(0)" ::: "memory");
    }
    G256_BAR();

    int cur = 0;
    for (int t = 0; t < NT; ++t) {
        const int k0 = t << 6;
        const ushort_t* LAc = LA0 + cur * 32768;
        const ushort_t* LBc = LB0 + cur * 32768;
        ushort_t* const nA  = sA + (cur ^ 1) * 32768;   // tile t+1 A dest
        ushort_t* const nB  = sB + cur * 32768;         // tile t+2 B dest

        bf16x8 bg[4][2], af[2][2];

        // -------- phase 0: read all B frags + A quad 0; stage A-half0(t+1) --------
        #pragma unroll
        for (int ni = 0; ni < 4; ni++)
            #pragma unroll
            for (int s = 0; s < 2; s++) {
                int lb = (brow + ni * 16 + r16) * 128 + s * 64 + kq * 16;
                lb ^= ((lb >> 7) & 7) << 4;
                bg[ni][s] = *reinterpret_cast<const bf16x8*>(LBc + (lb >> 1));
            }
        G256_READ_A(0);
        if (t + 1 < NT) stage_half256(A, tile_m, Kd, k0 + 64, nA, tid);
        G256_BAR();
        G256_LGKM0();
        G256_MFMA(0);
        G256_BAR();

        // -------- phase 1: A quad 1; stage A-half1(t+1) --------
        G256_READ_A(1);
        if (t + 1 < NT) stage_half256(A, tile_m + 128, Kd, k0 + 64, nA + 8192, tid);
        G256_BAR();
        G256_LGKM0();
        G256_MFMA(1);
        G256_BAR();

        // -------- phase 2: A quad 2; stage B-half0(t+2) (B of tile t fully read) --------
        G256_READ_A(2);
        if (t + 2 < NT) stage_half256(Bt, tile_n, Kd, k0 + 128, nB, tid);
        G256_BAR();
        G256_LGKM0();
        G256_MFMA(2);
        G256_BAR();

        // -------- phase 3: A quad 3; stage B-half1(t+2); counted vmcnt --------
        G256_READ_A(3);
        if (t + 2 < NT) stage_half256(Bt, tile_n + 128, Kd, k0 + 128, nB + 8192, tid);
        G256_BAR();
        G256_LGKM0();
        G256_MFMA(3);
        if (t + 2 < NT) { asm volatile("s_waitcnt vmcnt(4)" ::: "memory"); }
        else            { asm volatile("s_waitcnt vmcnt(0)" ::: "memory"); }
        G256_BAR();
        cur ^= 1;
    }

    // ---- epilogues (C/D layout: col = lane&15, row = (lane>>4)*4 + reg) ----
    if (MODE == 1) {
        float* C = (float*)Cv;
        #pragma unroll
        for (int mi = 0; mi < 8; mi++)
            #pragma unroll
            for (int ni = 0; ni < 4; ni++)
                #pragma unroll
                for (int r = 0; r < 4; r++) {
                    const int row = tile_m + wr * 128 + mi * 16 + kq * 4 + r;
                    const int col = tile_n + wc * 64 + ni * 16 + r16;
                    C[(long)row * N + col] =
                        acc[mi][ni][r] + bias[col] + resid[(long)row * N + col];
                }
    } else if (MODE == 2) {
        ushort_t* C = (ushort_t*)Cv + (long)bz * batchC;
        const float* rs = rowsum + (long)bz * 2048;
        #pragma unroll
        for (int mi = 0; mi < 8; mi++) {
            float inv[4];
            #pragma unroll
            for (int r = 0; r < 4; r++)
                inv[r] = 1.0f / rs[tile_m + wr * 128 + mi * 16 + kq * 4 + r];
            #pragma unroll
            for (int ni = 0; ni < 4; ni++)
                #pragma unroll
                for (int r = 0; r < 4; r++) {
                    const int row = tile_m + wr * 128 + mi * 16 + kq * 4 + r;
                    const int col = tile_n + wc * 64 + ni * 16 + r16;
                    C[(long)row * N + col] = f2b(acc[mi][ni][r] * inv[r]);
                }
        }
    } else if (MODE == 3) {
        ushort_t* C = (ushort_t*)Cv + (long)bz * batchC;
        float* rs = rowsum + (long)bz * 2048;
        #pragma unroll
        for (int mi = 0; mi < 8; mi++)
            #pragma unroll
            for (int r = 0; r < 4; r++) {
                const int row = tile_m + wr * 128 + mi * 16 + kq * 4 + r;
                float psum = 0.f;
                #pragma unroll
                for (int ni = 0; ni < 4; ni++) {
                    const float e = __expf(acc[mi][ni][r] * scale);
                    psum += e;
                    const int col = tile_n + wc * 64 + ni * 16 + r16;
                    C[(long)row * N + col] = f2b(e);
                }
                psum += __shfl_xor(psum, 1);
                psum += __shfl_xor(psum, 2);
                psum += __shfl_xor(psum, 4);
                psum += __shfl_xor(psum, 8);
                if (r16 == 0) atomicAdd(&rs[row], psum);
            }
    } else {
        // MODE 4: fused QKV. Cv = Qb base; sections of MROWS*768 each.
        const int sect  = tile_n / 768;          // 256-tile lies in one section
        const int ncol0 = tile_n - sect * 768;
        if (sect == 2) {
            // V: write TRANSPOSED directly -> Vt[b][d][s]  (Vt passed via rowsum)
            ushort_t* Vt = (ushort_t*)rowsum;
            #pragma unroll
            for (int mi = 0; mi < 8; mi++)
                #pragma unroll
                for (int ni = 0; ni < 4; ni++) {
                    const int row = tile_m + wr * 128 + mi * 16 + kq * 4;
                    const int d   = ncol0 + wc * 64 + ni * 16 + r16;
                    const int b   = row >> 11, s = row & 2047;
                    ushort4 o;
                    o.x = f2b(acc[mi][ni][0]); o.y = f2b(acc[mi][ni][1]);
                    o.z = f2b(acc[mi][ni][2]); o.w = f2b(acc[mi][ni][3]);
                    *(ushort4*)(Vt + (long)b * ((long)2048 * 768) + (long)d * 2048 + s) = o;
                }
        } else {
            ushort_t* C = (ushort_t*)Cv + (size_t)sect * ((size_t)MROWS * 768);
            const float sc = (sect == 0) ? scale : 1.0f;
            #pragma unroll
            for (int mi = 0; mi < 8; mi++)
                #pragma unroll
                for (int ni = 0; ni < 4; ni++)
                    #pragma unroll
                    for (int r = 0; r < 4; r++) {
                        const int row = tile_m + wr * 128 + mi * 16 + kq * 4 + r;
                        const int col = ncol0 + wc * 64 + ni * 16 + r16;
                        C[(long)row * 768 + col] = f2b(acc[mi][ni][r] * sc);
                    }
        }
    }
}

// ---------------------------------------------------------------------------
// m97-structure 128^2 NT GEMM (kept for non-batched ws path)
// ---------------------------------------------------------------------------
template<int MODE>
__global__ __launch_bounds__(256)
void gemm_nt(const ushort_t* __restrict__ A, const ushort_t* __restrict__ Bt,
             void* __restrict__ Cv, int M, int N, int Kd,
             long batchA, long batchB, long batchC, float scale,
             const float* __restrict__ bias, const float* __restrict__ resid,
             float* __restrict__ rowsum)
{
    __shared__ __align__(16) ushort_t As[128 * 32];
    __shared__ __align__(16) ushort_t Bs[128 * 32];

    const int bz = blockIdx.z;
    A  += (long)bz * batchA;
    Bt += (long)bz * batchB;

    const int nxt  = gridDim.x;
    const int nblk = nxt * gridDim.y;
    int lin = blockIdx.y * nxt + blockIdx.x;
    if ((nblk & 7) == 0) {
        const int per = nblk >> 3;
        lin = (lin & 7) * per + (lin >> 3);
    }
    const int tile_n = (lin % nxt) * 128;
    const int tile_m = (lin / nxt) * 128;

    const int tid  = threadIdx.x;
    const int w    = tid >> 6;
    const int lane = tid & 63;
    const int wr = w >> 1, wc = w & 1;
    const int r16 = lane & 15;
    const int kq  = lane >> 4;

    const int srow   = lane >> 2;
    const int schunk = lane & 3;
    const int arow0 = w * 32 + srow;
    const int arow1 = arow0 + 16;
    const int g0 = (schunk ^ ((arow0 >> 1) & 3)) * 8;
    const int g1 = (schunk ^ ((arow1 >> 1) & 3)) * 8;

    const ushort_t* Ar0 = A  + (long)(tile_m + arow0) * Kd + g0;
    const ushort_t* Ar1 = A  + (long)(tile_m + arow1) * Kd + g1;
    const ushort_t* Br0 = Bt + (long)(tile_n + arow0) * Kd + g0;
    const ushort_t* Br1 = Bt + (long)(tile_n + arow1) * Kd + g1;

    ushort_t* lA0 = &As[(w * 32     ) * 32];
    ushort_t* lA1 = &As[(w * 32 + 16) * 32];
    ushort_t* lB0 = &Bs[(w * 32     ) * 32];
    ushort_t* lB1 = &Bs[(w * 32 + 16) * 32];

    f32x4 acc[4][4] = {};

    for (int k0 = 0; k0 < Kd; k0 += 32) {
        gload16(Ar0 + k0, lA0);
        gload16(Ar1 + k0, lA1);
        gload16(Br0 + k0, lB0);
        gload16(Br1 + k0, lB1);
        __syncthreads();

        bf16x8 af[4], bg[4];
        #pragma unroll
        for (int i = 0; i < 4; i++) {
            const int ra = wr * 64 + i * 16 + r16;
            af[i] = *reinterpret_cast<const bf16x8*>(&As[ra * 32 + ((kq ^ ((ra >> 1) & 3)) * 8)]);
            const int rb = wc * 64 + i * 16 + r16;
            bg[i] = *reinterpret_cast<const bf16x8*>(&Bs[rb * 32 + ((kq ^ ((rb >> 1) & 3)) * 8)]);
        }
        #pragma unroll
        for (int mi = 0; mi < 4; mi++)
            #pragma unroll
            for (int ni = 0; ni < 4; ni++)
                acc[mi][ni] = __builtin_amdgcn_mfma_f32_16x16x32_bf16(af[mi], bg[ni], acc[mi][ni], 0, 0, 0);
        __syncthreads();
    }

    if (MODE == 0) {
        ushort_t* C = (ushort_t*)Cv + (long)bz * batchC;
        #pragma unroll
        for (int mi = 0; mi < 4; mi++)
            #pragma unroll
            for (int ni = 0; ni < 4; ni++)
                #pragma unroll
                for (int r = 0; r < 4; r++) {
                    const int row = tile_m + wr * 64 + mi * 16 + kq * 4 + r;
                    const int col = tile_n + wc * 64 + ni * 16 + r16;
                    C[(long)row * N + col] = f2b(acc[mi][ni][r] * scale);
                }
    } else if (MODE == 1) {
        float* C = (float*)Cv;
        #pragma unroll
        for (int mi = 0; mi < 4; mi++)
            #pragma unroll
            for (int ni = 0; ni < 4; ni++)
                #pragma unroll
                for (int r = 0; r < 4; r++) {
                    const int row = tile_m + wr * 64 + mi * 16 + kq * 4 + r;
                    const int col = tile_n + wc * 64 + ni * 16 + r16;
                    C[(long)row * N + col] =
                        acc[mi][ni][r] + bias[col] + resid[(long)row * N + col];
                }
    } else if (MODE == 2) {
        ushort_t* C = (ushort_t*)Cv + (long)bz * batchC;
        const float* rs = rowsum + (long)bz * 2048;
        #pragma unroll
        for (int mi = 0; mi < 4; mi++) {
            float inv[4];
            #pragma unroll
            for (int r = 0; r < 4; r++)
                inv[r] = 1.0f / rs[tile_m + wr * 64 + mi * 16 + kq * 4 + r];
            #pragma unroll
            for (int ni = 0; ni < 4; ni++)
                #pragma unroll
                for (int r = 0; r < 4; r++) {
                    const int row = tile_m + wr * 64 + mi * 16 + kq * 4 + r;
                    const int col = tile_n + wc * 64 + ni * 16 + r16;
                    C[(long)row * N + col] = f2b(acc[mi][ni][r] * inv[r]);
                }
        }
    } else if (MODE == 3) {
        ushort_t* C = (ushort_t*)Cv + (long)bz * batchC;
        float* rs = rowsum + (long)bz * 2048;
        #pragma unroll
        for (int mi = 0; mi < 4; mi++)
            #pragma unroll
            for (int r = 0; r < 4; r++) {
                const int row = tile_m + wr * 64 + mi * 16 + kq * 4 + r;
                float psum = 0.f;
                #pragma unroll
                for (int ni = 0; ni < 4; ni++) {
                    const float e = __expf(acc[mi][ni][r] * scale);
                    psum += e;
                    const int col = tile_n + wc * 64 + ni * 16 + r16;
                    C[(long)row * N + col] = f2b(e);
                }
                psum += __shfl_xor(psum, 1);
                psum += __shfl_xor(psum, 2);
                psum += __shfl_xor(psum, 4);
                psum += __shfl_xor(psum, 8);
                if (r16 == 0) atomicAdd(&rs[row], psum);
            }
    } else {
        const int sect  = tile_n / 768;
        const int ncol0 = tile_n - sect * 768;
        ushort_t* C = (ushort_t*)Cv + (size_t)sect * ((size_t)MROWS * 768);
        const float sc = (sect == 0) ? scale : 1.0f;
        #pragma unroll
        for (int mi = 0; mi < 4; mi++)
            #pragma unroll
            for (int ni = 0; ni < 4; ni++)
                #pragma unroll
                for (int r = 0; r < 4; r++) {
                    const int row = tile_m + wr * 64 + mi * 16 + kq * 4 + r;
                    const int col = ncol0 + wc * 64 + ni * 16 + r16;
                    C[(long)row * 768 + col] = f2b(acc[mi][ni][r] * sc);
                }
    }
}

// ---------------------------------------------------------------------------
// Fallback GEMM (round-3 proven) — only if ws too small for fast paths
// ---------------------------------------------------------------------------
template<int TRANSB, int MODE, int BF32>
__global__ __launch_bounds__(256)
void gemm_s(const ushort_t* __restrict__ A, const void* __restrict__ Bsrc,
            void* __restrict__ Cv, int M, int N, int Kd, float scale,
            const float* __restrict__ bias, const float* __restrict__ resid)
{
    __shared__ __align__(16) ushort_t As[128 * LDST];
    __shared__ __align__(16) ushort_t Bs[128 * LDST];
    const int tile_n = blockIdx.x * 128;
    const int tile_m = blockIdx.y * 128;
    const int tid  = threadIdx.x;
    const int w    = tid >> 6;
    const int lane = tid & 63;
    const int wr = w >> 1, wc = w & 1;
    const int r16 = lane & 15;
    const int kq  = lane >> 4;
    f32x4 acc[4][4] = {};
    for (int k0 = 0; k0 < Kd; k0 += 32) {
        #pragma unroll
        for (int cc = 0; cc < 2; cc++) {
            const int c = tid + cc * 256;
            const int row = c >> 2, col = (c & 3) * 8;
            *(uint4*)&As[row * LDST + col] = *(const uint4*)(A + (long)(tile_m + row) * Kd + k0 + col);
        }
        if (TRANSB == 0) {
            const ushort_t* Bt = (const ushort_t*)Bsrc;
            #pragma unroll
            for (int cc = 0; cc < 2; cc++) {
                const int c = tid + cc * 256;
                const int row = c >> 2, col = (c & 3) * 8;
                *(uint4*)&Bs[row * LDST + col] = *(const uint4*)(Bt + (long)(tile_n + row) * Kd + k0 + col);
            }
        } else {
            #pragma unroll
            for (int i = 0; i < 16; i++) {
                const int lin = i * 256 + tid;
                const int kr = lin >> 7, nc = lin & 127;
                ushort_t bv;
                if (BF32) bv = f2b(((const float*)Bsrc)[(long)(k0 + kr) * N + tile_n + nc]);
                else      bv = ((const ushort_t*)Bsrc)[(long)(k0 + kr) * N + tile_n + nc];
                Bs[nc * LDST + kr] = bv;
            }
        }
        __syncthreads();
        bf16x8 af[4], bg[4];
        #pragma unroll
        for (int i = 0; i < 4; i++) {
            af[i] = *reinterpret_cast<const bf16x8*>(&As[(wr * 64 + i * 16 + r16) * LDST + kq * 8]);
            bg[i] = *reinterpret_cast<const bf16x8*>(&Bs[(wc * 64 + i * 16 + r16) * LDST + kq * 8]);
        }
        #pragma unroll
        for (int mi = 0; mi < 4; mi++)
            #pragma unroll
            for (int ni = 0; ni < 4; ni++)
                acc[mi][ni] = __builtin_amdgcn_mfma_f32_16x16x32_bf16(af[mi], bg[ni], acc[mi][ni], 0, 0, 0);
        __syncthreads();
    }
    if (MODE == 0) {
        ushort_t* C = (ushort_t*)Cv;
        #pragma unroll
        for (int mi = 0; mi < 4; mi++)
            #pragma unroll
            for (int ni = 0; ni < 4; ni++)
                #pragma unroll
                for (int r = 0; r < 4; r++) {
                    const int row = tile_m + wr * 64 + mi * 16 + kq * 4 + r;
                    const int col = tile_n + wc * 64 + ni * 16 + r16;
                    C[(long)row * N + col] = f2b(acc[mi][ni][r] * scale);
                }
    } else {
        float* C = (float*)Cv;
        #pragma unroll
        for (int mi = 0; mi < 4; mi++)
            #pragma unroll
            for (int ni = 0; ni < 4; ni++)
                #pragma unroll
                for (int r = 0; r < 4; r++) {
                    const int row = tile_m + wr * 64 + mi * 16 + kq * 4 + r;
                    const int col = tile_n + wc * 64 + ni * 16 + r16;
                    C[(long)row * N + col] =
                        acc[mi][ni][r] + bias[col] + resid[(long)row * N + col];
                }
    }
}

// softmax over rows of 2048 bf16 (fallback path only)
__global__ void softmax_rows(ushort_t* __restrict__ p)
{
    __shared__ float sm[4], ss_[4];
    ushort_t* pr = p + (long)blockIdx.x * 2048;
    const int tid = threadIdx.x;
    const int w = tid >> 6;
    const uint4 raw = *(const uint4*)(pr + tid * 8);
    float v[8];
    v[0] = b2f((ushort_t)(raw.x & 0xffff)); v[1] = b2f((ushort_t)(raw.x >> 16));
    v[2] = b2f((ushort_t)(raw.y & 0xffff)); v[3] = b2f((ushort_t)(raw.y >> 16));
    v[4] = b2f((ushort_t)(raw.z & 0xffff)); v[5] = b2f((ushort_t)(raw.z >> 16));
    v[6] = b2f((ushort_t)(raw.w & 0xffff)); v[7] = b2f((ushort_t)(raw.w >> 16));
    float mx = -3.0e38f;
    #pragma unroll
    for (int i = 0; i < 8; i++) mx = fmaxf(mx, v[i]);
    #pragma unroll
    for (int off = 32; off; off >>= 1) mx = fmaxf(mx, __shfl_xor(mx, off));
    if ((tid & 63) == 0) sm[w] = mx;
    __syncthreads();
    mx = fmaxf(fmaxf(sm[0], sm[1]), fmaxf(sm[2], sm[3]));
    float s = 0.f;
    #pragma unroll
    for (int i = 0; i < 8; i++) { v[i] = __expf(v[i] - mx); s += v[i]; }
    #pragma unroll
    for (int off = 32; off; off >>= 1) s += __shfl_xor(s, off);
    if ((tid & 63) == 0) ss_[w] = s;
    __syncthreads();
    s = ss_[0] + ss_[1] + ss_[2] + ss_[3];
    const float inv = 1.f / s;
    uint4 o;
    o.x = f2b(v[0] * inv) | ((unsigned)f2b(v[1] * inv) << 16);
    o.y = f2b(v[2] * inv) | ((unsigned)f2b(v[3] * inv) << 16);
    o.z = f2b(v[4] * inv) | ((unsigned)f2b(v[5] * inv) << 16);
    o.w = f2b(v[6] * inv) | ((unsigned)f2b(v[7] * inv) << 16);
    *(uint4*)(pr + tid * 8) = o;
}

// double layernorm per fp32 row of 768, IN PLACE
__global__ void ln_fused(float* __restrict__ x,
                         const float* __restrict__ w1, const float* __restrict__ b1,
                         const float* __restrict__ w2, const float* __restrict__ b2)
{
    __shared__ float r1s[4], r1q[4], r2s[4], r2q[4];
    const long row = blockIdx.x;
    const int tid = threadIdx.x;
    const int w = tid >> 6;
    float* xr = x + row * 768;
    float v[3], s = 0.f, q = 0.f;
    #pragma unroll
    for (int i = 0; i < 3; i++) { const float t = xr[tid + i * 256]; v[i] = t; s += t; q += t * t; }
    #pragma unroll
    for (int off = 32; off; off >>= 1) { s += __shfl_xor(s, off); q += __shfl_xor(q, off); }
    if ((tid & 63) == 0) { r1s[w] = s; r1q[w] = q; }
    __syncthreads();
    s = r1s[0] + r1s[1] + r1s[2] + r1s[3];
    q = r1q[0] + r1q[1] + r1q[2] + r1q[3];
    float mu = s * (1.f / 768.f);
    float ri = rsqrtf(q * (1.f / 768.f) - mu * mu + EPS);
    float y[3];
    s = 0.f; q = 0.f;
    #pragma unroll
    for (int i = 0; i < 3; i++) {
        const int d = tid + i * 256;
        const float t = (v[i] - mu) * ri * w1[d] + b1[d];
        y[i] = t; s += t; q += t * t;
    }
    #pragma unroll
    for (int off = 32; off; off >>= 1) { s += __shfl_xor(s, off); q += __shfl_xor(q, off); }
    if ((tid & 63) == 0) { r2s[w] = s; r2q[w] = q; }
    __syncthreads();
    s = r2s[0] + r2s[1] + r2s[2] + r2s[3];
    q = r2q[0] + r2q[1] + r2q[2] + r2q[3];
    mu = s * (1.f / 768.f);
    ri = rsqrtf(q * (1.f / 768.f) - mu * mu + EPS);
    #pragma unroll
    for (int i = 0; i < 3; i++) {
        const int d = tid + i * 256;
        xr[d] = (y[i] - mu) * ri * w2[d] + b2[d];
    }
}

__global__ void pool_reduce(const float* __restrict__ x, float* __restrict__ pooled)
{
    const int d  = blockIdx.x * 256 + threadIdx.x;
    const int b  = blockIdx.z;
    const int sp = blockIdx.y;
    const float* base = x + ((long)b * 2048 + sp * 128) * 768 + d;
    float s = 0.f;
    #pragma unroll 8
    for (int i = 0; i < 128; i++) s += base[(long)i * 768];
    atomicAdd(&pooled[b * 768 + d], s);
}

// 80 blocks x 64 lanes: one wave per (b, o)
__global__ void logits_kernel(const float* __restrict__ pooled, const float* __restrict__ Wc,
                              const float* __restrict__ bc, float* __restrict__ out)
{
    const int b = blockIdx.x / 10, o = blockIdx.x % 10;
    const int lane = threadIdx.x;
    float s = 0.f;
    #pragma unroll
    for (int d = lane; d < 768; d += 64) s += pooled[b * 768 + d] * Wc[d * 10 + o];
    #pragma unroll
    for (int off = 32; off; off >>= 1) s += __shfl_xor(s, off);
    if (lane == 0) out[b * 10 + o] = s * (1.f / 2048.f) + bc[o];
}

extern "C" void kernel_launch(void* const* d_in, const int* in_sizes, int n_in,
                              void* d_out, int out_size, void* d_ws, size_t ws_size,
                              hipStream_t stream)
{
    (void)in_sizes; (void)n_in; (void)out_size;
    const float* src  = (const float*)d_in[0];
    const float* Wq   = (const float*)d_in[1];
    const float* Wk   = (const float*)d_in[2];
    const float* Wv   = (const float*)d_in[3];
    const float* Wo   = (const float*)d_in[4];
    const float* bo   = (const float*)d_in[5];
    const float* ln1w = (const float*)d_in[6];
    const float* ln1b = (const float*)d_in[7];
    const float* ln2w = (const float*)d_in[8];
    const float* ln2b = (const float*)d_in[9];
    const float* Wc   = (const float*)d_in[10];
    const float* bc   = (const float*)d_in[11];
    float* out = (float*)d_out;

    const dim3 blk(256);
    const dim3 blk512(512);
    const float qscale = 1.0f / sqrtf(768.0f);
    const long bs = (long)2048 * 768;

    const size_t WT    = (size_t)768 * 768 * 2;          // 256-mult: Wt bufs contiguous
    const size_t BUF   = (size_t)MROWS * 768 * 2;        // 256-mult: Q/K/V contiguous
    const size_t POOLB = 24576;
    const size_t RSB   = (size_t)B_ * 2048 * 4;          // rowsum, 64 KB
    const size_t PROBS8 = (size_t)8 * 2048 * 2048 * 2;
    const size_t needB = 4 * WT + 5 * BUF + POOLB + RSB;  // ~130.7 MB
    const size_t needA = needB + PROBS8;                  // ~197.8 MB

    char* ws = (char*)d_ws;
    size_t off = 0;
    auto alloc = [&](size_t bytes) { void* p = ws + off; off += (bytes + 255) & ~(size_t)255; return p; };

    if (ws_size >= needB) {
        ushort_t* Wtq  = (ushort_t*)alloc(WT);   // Wtq/Wtk/Wtv contiguous => fused QKV B operand
        ushort_t* Wtk  = (ushort_t*)alloc(WT);
        ushort_t* Wtv  = (ushort_t*)alloc(WT);
        ushort_t* Wto  = (ushort_t*)alloc(WT);
        ushort_t* srcb = (ushort_t*)alloc(BUF);
        ushort_t* Qb   = (ushort_t*)alloc(BUF);  // Qb/Kb/Vb contiguous => MODE 4 sect routing
        ushort_t* Kb   = (ushort_t*)alloc(BUF);
        ushort_t* Vb   = (ushort_t*)alloc(BUF);  // untouched by QKV (V goes to Vt); reused as attn
        ushort_t* Vt   = (ushort_t*)alloc(BUF);  // written DIRECTLY by QKV epilogue (transposed)
        float*  pooled = (float*)  alloc(POOLB);
        float*  rowsum = (float*)  alloc(RSB);
        const bool batched = (ws_size >= needA);
        ushort_t* probs = batched ? (ushort_t*)alloc(PROBS8) : srcb;  // srcb dead after QKV
        ushort_t* attn  = Vb;
        float*    xpre  = out + 80;
        (void)Wtk; (void)Wtv;

        cast_f32_bf16<<<MROWS * 768 / 1024, blk, 0, stream>>>(src, srcb, (long)MROWS * 768);
        transpose_w4<<<dim3(12, 12, 4), blk, 0, stream>>>(Wq, Wk, Wv, Wo, Wtq);

        // fused QKV: [16384,768] @ [2304,768]^T; Q/K -> Qb/Kb, V -> Vt (transposed in epilogue)
        gemm256<4><<<dim3(576), blk512, 0, stream>>>(srcb, Wtq, Qb, MROWS, 2304, 768,
                                                     0, 0, 0, qscale, nullptr, nullptr, (float*)Vt);

        hipMemsetAsync(rowsum, 0, RSB, stream);

        if (batched) {
            // scores: exp(QK^T) with fused row-sum atomics; M-stationary decode
            gemm256<3><<<dim3(512), blk512, 0, stream>>>(Qb, Kb, probs, 2048, 2048, 768,
                                                         bs, bs, (long)2048 * 2048, 1.0f,
                                                         nullptr, nullptr, rowsum);
            // PV: normalize by rowsum in epilogue; M-stationary decode
            gemm256<2><<<dim3(192), blk512, 0, stream>>>(probs, Vt, attn, 2048, 768, 2048,
                                                         (long)2048 * 2048, bs, bs, 1.0f,
                                                         nullptr, nullptr, rowsum);
        } else {
            for (int bz = 0; bz < B_; bz += 2) {
                gemm_nt<3><<<dim3(16, 16, 2), blk, 0, stream>>>(Qb + bz * bs, Kb + bz * bs, probs,
                                                                2048, 2048, 768, bs, bs, (long)2048 * 2048,
                                                                1.0f, nullptr, nullptr, rowsum + bz * 2048);
                gemm_nt<2><<<dim3(6, 16, 2), blk, 0, stream>>>(probs, Vt + bz * bs, attn + bz * bs,
                                                               2048, 768, 2048,
                                                               (long)2048 * 2048, bs, bs, 1.0f,
                                                               nullptr, nullptr, rowsum + bz * 2048);
            }
        }

        gemm256<1><<<dim3(192), blk512, 0, stream>>>(attn, Wto, xpre, MROWS, 768, 768,
                                                     0, 0, 0, 1.0f, bo, src, nullptr);
        ln_fused<<<MROWS, blk, 0, stream>>>(xpre, ln1w, ln1b, ln2w, ln2b);
        hipMemsetAsync(pooled, 0, B_ * 768 * 4, stream);
        pool_reduce<<<dim3(3, 16, B_), blk, 0, stream>>>(xpre, pooled);
        logits_kernel<<<80, 64, 0, stream>>>(pooled, Wc, bc, out);
    } else {
        // round-3 proven fallback (~100.7 MB)
        ushort_t* srcb = (ushort_t*)alloc(BUF);
        ushort_t* Qb   = (ushort_t*)alloc(BUF);
        ushort_t* Kb   = (ushort_t*)alloc(BUF);
        ushort_t* Vb   = (ushort_t*)alloc(BUF);
        float*  pooled = (float*)  alloc(POOLB);
        ushort_t* probs = srcb;
        ushort_t* attn  = Qb;
        float*    xpre  = out + 80;

        cast_f32_bf16<<<MROWS * 768 / 1024, blk, 0, stream>>>(src, srcb, (long)MROWS * 768);
        gemm_s<1, 0, 1><<<dim3(6, 128), blk, 0, stream>>>(srcb, Wq, Qb, MROWS, 768, 768, qscale, nullptr, nullptr);
        gemm_s<1, 0, 1><<<dim3(6, 128), blk, 0, stream>>>(srcb, Wk, Kb, MROWS, 768, 768, 1.0f, nullptr, nullptr);
        gemm_s<1, 0, 1><<<dim3(6, 128), blk, 0, stream>>>(srcb, Wv, Vb, MROWS, 768, 768, 1.0f, nullptr, nullptr);
        for (int bz = 0; bz < B_; bz++) {
            gemm_s<0, 0, 0><<<dim3(16, 16), blk, 0, stream>>>(Qb + bz * bs, Kb + bz * bs, probs,
                                                              2048, 2048, 768, 1.0f, nullptr, nullptr);
            softmax_rows<<<2048, blk, 0, stream>>>(probs);
            gemm_s<1, 0, 0><<<dim3(6, 16), blk, 0, stream>>>(probs, Vb + bz * bs, attn + bz * bs,
                                                             2048, 768, 2048, 1.0f, nullptr, nullptr);
        }
        gemm_s<1, 1, 1><<<dim3(6, 128), blk, 0, stream>>>(attn, Wo, xpre, MROWS, 768, 768, 1.0f, bo, src);
        ln_fused<<<MROWS, blk, 0, stream>>>(xpre, ln1w, ln1b, ln2w, ln2b);
        hipMemsetAsync(pooled, 0, B_ * 768 * 4, stream);
        pool_reduce<<<dim3(3, 16, B_), blk, 0, stream>>>(xpre, pooled);
        logits_kernel<<<80, 64, 0, stream>>>(pooled, Wc, bc, out);
    }
}

// Round 9
// 419.511 us; speedup vs baseline: 1.0333x; 1.0090x over previous
//
#include <hip/hip_runtime.h>
#include <cmath>

typedef unsigned short ushort_t;
typedef __bf16 bf16x8 __attribute__((ext_vector_type(8)));
typedef float  f32x4  __attribute__((ext_vector_type(4)));

#define B_  8
#define S_  2048
#define D_  768
#define MROWS (B_ * S_)       // 16384
#define EPS 1e-5f
#define LDST 40               // padded stride for fallback gemm only

__device__ __forceinline__ float b2f(ushort_t u) {
    union { unsigned int i; float f; } v; v.i = ((unsigned int)u) << 16; return v.f;
}
__device__ __forceinline__ ushort_t f2b(float f) {
    union { float f; unsigned int i; } v; v.f = f;
    unsigned int r = v.i + 0x7fffu + ((v.i >> 16) & 1u);
    return (ushort_t)(r >> 16);
}

// async 16B global->LDS; LDS dest = wave-uniform base + lane*16
__device__ __forceinline__ void gload16(const ushort_t* g, ushort_t* l) {
    __builtin_amdgcn_global_load_lds((__attribute__((address_space(1))) void*)g,
                                     (__attribute__((address_space(3))) void*)l,
                                     16, 0, 0);
}

// fp32 -> bf16 cast, 4 elems/thread (fallback path)
__global__ void cast_f32_bf16(const float* __restrict__ in, ushort_t* __restrict__ outp, long n)
{
    const long i = ((long)blockIdx.x * 256 + threadIdx.x) * 4;
    if (i + 3 < n) {
        const float4 v = *(const float4*)(in + i);
        ushort4 o;
        o.x = f2b(v.x); o.y = f2b(v.y); o.z = f2b(v.z); o.w = f2b(v.w);
        *(ushort4*)(outp + i) = o;
    }
}

// ---------------------------------------------------------------------------
// prep: ONE dispatch doing {src cast -> bf16} || {4x 768x768 weight
// transpose+cast} || {zero rowsum (16384 f32) + pooled (6144 f32)}.
// All three are independent; collapsing 4 launches (cast, transpose_w4,
// 2 memsets) into 1 removes ~3 launch gaps and hides transpose/zero under
// the cast's HBM time. Zeroing early is safe: rowsum/pooled are first
// touched by scores/pool_reduce dispatches (MODE 4's rowsum arg carries Vt,
// not the real rowsum buffer).
// blocks [0,12288): cast; [12288,12864): transposes; [12864,12952): zeroes
// ---------------------------------------------------------------------------
__global__ void prep(const float* __restrict__ src, ushort_t* __restrict__ srcb,
                     const float* __restrict__ w0, const float* __restrict__ w1,
                     const float* __restrict__ w2, const float* __restrict__ w3,
                     ushort_t* __restrict__ wdst,
                     float* __restrict__ rowsum, float* __restrict__ pooled)
{
    const int bb  = blockIdx.x;
    const int tid = threadIdx.x;
    if (bb < 12288) {
        const long i = ((long)bb * 256 + tid) * 4;
        const float4 v = *(const float4*)(src + i);
        ushort4 o;
        o.x = f2b(v.x); o.y = f2b(v.y); o.z = f2b(v.z); o.w = f2b(v.w);
        *(ushort4*)(srcb + i) = o;
    } else if (bb < 12864) {
        __shared__ ushort_t tile[64 * 65];
        const int zb  = bb - 12288;
        const int zi  = zb / 144;
        const int rem = zb - zi * 144;
        const float* s = (zi == 0) ? w0 : (zi == 1) ? w1 : (zi == 2) ? w2 : w3;
        ushort_t* dst = wdst + (size_t)zi * ((size_t)768 * 768);
        const int r0 = (rem / 12) * 64, c0 = (rem % 12) * 64;
        const int tr = tid >> 6, tc = tid & 63;
        #pragma unroll
        for (int i = 0; i < 16; i++) {
            const int r = i * 4 + tr;
            tile[r * 65 + tc] = f2b(s[(long)(r0 + r) * 768 + (c0 + tc)]);
        }
        __syncthreads();
        #pragma unroll
        for (int i = 0; i < 16; i++) {
            const int r = i * 4 + tr;
            dst[(long)(c0 + r) * 768 + (r0 + tc)] = tile[tc * 65 + r];
        }
    } else {
        const int idx = (bb - 12864) * 256 + tid;   // [0, 22528)
        if (idx < 16384)      rowsum[idx] = 0.f;
        else                  pooled[idx - 16384] = 0.f;
    }
}

// ---------------------------------------------------------------------------
// transpose (fallback path only)
// ---------------------------------------------------------------------------
template<int F32IN>
__global__ void transpose_any(const void* __restrict__ srcv, ushort_t* __restrict__ dst,
                              int R, int C, long sb, long db)
{
    __shared__ ushort_t tile[64 * 65];
    dst += (long)blockIdx.z * db;
    const int r0 = blockIdx.y * 64, c0 = blockIdx.x * 64;
    const int t = threadIdx.x;
    const int tr = t >> 6, tc = t & 63;
    #pragma unroll
    for (int i = 0; i < 16; i++) {
        const int r = i * 4 + tr;
        ushort_t v;
        if (F32IN) v = f2b(((const float*)srcv + (long)blockIdx.z * sb)[(long)(r0 + r) * C + (c0 + tc)]);
        else       v = ((const ushort_t*)srcv + (long)blockIdx.z * sb)[(long)(r0 + r) * C + (c0 + tc)];
        tile[r * 65 + tc] = v;
    }
    __syncthreads();
    #pragma unroll
    for (int i = 0; i < 16; i++) {
        const int r = i * 4 + tr;
        dst[(long)(c0 + r) * R + (r0 + tc)] = tile[tc * 65 + r];
    }
}

// ===========================================================================
// gemm256: 256x256-tile, BK=64, 8-wave, 8-phase deep-pipelined NT GEMM
// (m201 template: T1 xcd-swz + T2 LDS swizzle + T3/T4 counted vmcnt
//  + T5 setprio).  C[M,N] = A[M,K] * Bt[N,K]^T, bf16 in, fp32 acc.
//
// GRID IS 1-D. Hardware XCD = blockIdx.x % 8; swizzle chunks the full grid
// per-XCD. Decode: rowf-dims ordered (tile_m OUTER, bz INNER) -> each XCD is
// sole reader of its A row-panels; all XCDs sweep the same B-tile
// co-temporally (L3-served once). FETCH verified minimal (55MB, R8).
// [Decode tuning is EXHAUSTED: R6/R7/R8 variants moved e2e within noise
//  (420-423) except R7's col-major which doubled FETCH. Do not re-tune.]
//
// K-loop structure is the R2-PROVEN form (conflicts 0). Do NOT re-add:
// lgkmcnt(N) pre-barrier throttles, hoisted 64-bit address lambdas (R3: -22%).
//
// MODE 1: C (fp32) = acc + bias[col] + resid[row*N+col]
// MODE 2: C (bf16) = acc / rowsum[bz*2048 + row]            (PV, normalize)
// MODE 3: C (bf16) = exp(acc*scale); atomicAdd row sums     (scores, fused softmax)
// MODE 4: QKV split: Cv=Qb base; sect=tile_n/768 routes to Q/K/V; qscale on Q
//         sect==2 (V) writes TRANSPOSED directly to Vt (passed via rowsum)
// ===========================================================================

// stage one 128x64 bf16 half-tile (16 KB): 2 x gload16 per thread.
// LDS dest linear; swizzle involution pre-applied to the GLOBAL source column.
__device__ __forceinline__ void stage_half256(const ushort_t* __restrict__ g, int row0,
                                              int Kd, int k0, ushort_t* l, int tid)
{
    #pragma unroll
    for (int i = 0; i < 2; i++) {
        const int c   = i * 512 + tid;          // 16B chunk index, 0..1023
        const int row = c >> 3;                 // 0..127
        const int scol = ((c & 7) ^ (row & 7)) * 8;  // src col, swizzle involution
        gload16(g + (long)(row0 + row) * Kd + (k0 + scol), l + c * 8);
    }
}

#define G256_BAR() do { \
    asm volatile("" ::: "memory"); \
    __builtin_amdgcn_s_barrier(); \
    asm volatile("" ::: "memory"); \
} while (0)

#define G256_LGKM0() asm volatile("s_waitcnt lgkmcnt(0)" ::: "memory")

#define G256_READ_A(q) do { \
    _Pragma("unroll") \
    for (int m2 = 0; m2 < 2; m2++) { \
        _Pragma("unroll") \
        for (int s = 0; s < 2; s++) { \
            int lb = (((q) * 2 + m2) * 16 + r16) * 128 + s * 64 + kq * 16; \
            lb ^= ((lb >> 7) & 7) << 4; \
            af[m2][s] = *reinterpret_cast<const bf16x8*>(LAc + (lb >> 1)); \
        } \
    } \
} while (0)

#define G256_MFMA(q) do { \
    __builtin_amdgcn_s_setprio(1); \
    _Pragma("unroll") \
    for (int m2 = 0; m2 < 2; m2++) { \
        _Pragma("unroll") \
        for (int ni = 0; ni < 4; ni++) { \
            acc[(q) * 2 + m2][ni] = __builtin_amdgcn_mfma_f32_16x16x32_bf16(af[m2][0], bg[ni][0], acc[(q) * 2 + m2][ni], 0, 0, 0); \
            acc[(q) * 2 + m2][ni] = __builtin_amdgcn_mfma_f32_16x16x32_bf16(af[m2][1], bg[ni][1], acc[(q) * 2 + m2][ni], 0, 0, 0); \
        } \
    } \
    __builtin_amdgcn_s_setprio(0); \
} while (0)

template<int MODE>
__global__ __launch_bounds__(512, 2)
void gemm256(const ushort_t* __restrict__ A, const ushort_t* __restrict__ Bt,
             void* __restrict__ Cv, int M, int N, int Kd,
             long batchA, long batchB, long batchC, float scale,
             const float* __restrict__ bias, const float* __restrict__ resid,
             float* __restrict__ rowsum)
{
    // [buf 0/1][A0,A1,B0,B1][128*64 bf16]  = 128 KiB
    __shared__ __align__(16) ushort_t lds[65536];

    // ---- XCD-aware swizzle over the FULL 1-D grid (hardware: x%8 -> XCD) ----
    const int nblk = gridDim.x;
    int lin = blockIdx.x;
    if ((nblk & 7) == 0) {
        const int per = nblk >> 3;
        lin = (lin & 7) * per + (lin >> 3);
    }
    const int ntN   = N >> 8;          // 256-tiles along N
    const int ntM   = M >> 8;          // 256-tiles along M
    const int nrows = nblk / ntN;      // = ntM * nbatch
    const int nb    = nrows / ntM;     // batch count
    const int colf = lin % ntN;
    const int rowf = lin / ntN;
    // batch-INNER decode: tile_m from chunk (stationary A-panel per XCD),
    // (bz, colf) from within-chunk index (co-temporal B across XCDs)
    const int bz     = rowf % nb;
    const int tile_m = (rowf / nb) * 256;
    const int tile_n = colf * 256;

    A  += (long)bz * batchA;
    Bt += (long)bz * batchB;

    const int tid  = threadIdx.x;
    const int w    = tid >> 6;
    const int lane = tid & 63;
    const int wr   = w >> 2;          // 0..1  (M-dim wave)
    const int wc   = w & 3;           // 0..3  (N-dim wave)
    const int r16  = lane & 15;
    const int kq   = lane >> 4;
    const int brow = (wc & 1) * 64;   // B row base within the wave's B-half

    const int NT = Kd >> 6;           // K-tiles of 64

    // element offsets: buf b base = b*32768; A0=+0 A1=+8192 B0=+16384 B1=+24576
    ushort_t* const sA = lds;
    ushort_t* const sB = lds + 16384;
    const ushort_t* const LA0 = lds + wr * 8192;
    const ushort_t* const LB0 = lds + 16384 + (wc >> 1) * 8192;

    f32x4 acc[8][4] = {};

    // ---- prologue: tile0 {A0,A1,B0,B1} + tile1 {B0,B1} ----
    stage_half256(A,  tile_m,       Kd, 0,  sA,         tid);
    stage_half256(A,  tile_m + 128, Kd, 0,  sA + 8192,  tid);
    stage_half256(Bt, tile_n,       Kd, 0,  sB,         tid);
    stage_half256(Bt, tile_n + 128, Kd, 0,  sB + 8192,  tid);
    if (NT > 1) {
        stage_half256(Bt, tile_n,       Kd, 64, sB + 32768,        tid);
        stage_half256(Bt, tile_n + 128, Kd, 64, sB + 32768 + 8192, tid);
        asm volatile("s_waitcnt vmcnt(4)" ::: "memory");   // tile0 landed
    } else {
        asm volatile("s_waitcnt vmcnt(0)" ::: "memory");
    }
    G256_BAR();

    int cur = 0;
    for (int t = 0; t < NT; ++t) {
        const int k0 = t << 6;
        const ushort_t* LAc = LA0 + cur * 32768;
        const ushort_t* LBc = LB0 + cur * 32768;
        ushort_t* const nA  = sA + (cur ^ 1) * 32768;   // tile t+1 A dest
        ushort_t* const nB  = sB + cur * 32768;         // tile t+2 B dest

        bf16x8 bg[4][2], af[2][2];

        // -------- phase 0: read all B frags + A quad 0; stage A-half0(t+1) --------
        #pragma unroll
        for (int ni = 0; ni < 4; ni++)
            #pragma unroll
            for (int s = 0; s < 2; s++) {
                int lb = (brow + ni * 16 + r16) * 128 + s * 64 + kq * 16;
                lb ^= ((lb >> 7) & 7) << 4;
                bg[ni][s] = *reinterpret_cast<const bf16x8*>(LBc + (lb >> 1));
            }
        G256_READ_A(0);
        if (t + 1 < NT) stage_half256(A, tile_m, Kd, k0 + 64, nA, tid);
        G256_BAR();
        G256_LGKM0();
        G256_MFMA(0);
        G256_BAR();

        // -------- phase 1: A quad 1; stage A-half1(t+1) --------
        G256_READ_A(1);
        if (t + 1 < NT) stage_half256(A, tile_m + 128, Kd, k0 + 64, nA + 8192, tid);
        G256_BAR();
        G256_LGKM0();
        G256_MFMA(1);
        G256_BAR();

        // -------- phase 2: A quad 2; stage B-half0(t+2) (B of tile t fully read) --------
        G256_READ_A(2);
        if (t + 2 < NT) stage_half256(Bt, tile_n, Kd, k0 + 128, nB, tid);
        G256_BAR();
        G256_LGKM0();
        G256_MFMA(2);
        G256_BAR();

        // -------- phase 3: A quad 3; stage B-half1(t+2); counted vmcnt --------
        G256_READ_A(3);
        if (t + 2 < NT) stage_half256(Bt, tile_n + 128, Kd, k0 + 128, nB + 8192, tid);
        G256_BAR();
        G256_LGKM0();
        G256_MFMA(3);
        if (t + 2 < NT) { asm volatile("s_waitcnt vmcnt(4)" ::: "memory"); }
        else            { asm volatile("s_waitcnt vmcnt(0)" ::: "memory"); }
        G256_BAR();
        cur ^= 1;
    }

    // ---- epilogues (C/D layout: col = lane&15, row = (lane>>4)*4 + reg) ----
    if (MODE == 1) {
        float* C = (float*)Cv;
        #pragma unroll
        for (int mi = 0; mi < 8; mi++)
            #pragma unroll
            for (int ni = 0; ni < 4; ni++)
                #pragma unroll
                for (int r = 0; r < 4; r++) {
                    const int row = tile_m + wr * 128 + mi * 16 + kq * 4 + r;
                    const int col = tile_n + wc * 64 + ni * 16 + r16;
                    C[(long)row * N + col] =
                        acc[mi][ni][r] + bias[col] + resid[(long)row * N + col];
                }
    } else if (MODE == 2) {
        ushort_t* C = (ushort_t*)Cv + (long)bz * batchC;
        const float* rs = rowsum + (long)bz * 2048;
        #pragma unroll
        for (int mi = 0; mi < 8; mi++) {
            float inv[4];
            #pragma unroll
            for (int r = 0; r < 4; r++)
                inv[r] = 1.0f / rs[tile_m + wr * 128 + mi * 16 + kq * 4 + r];
            #pragma unroll
            for (int ni = 0; ni < 4; ni++)
                #pragma unroll
                for (int r = 0; r < 4; r++) {
                    const int row = tile_m + wr * 128 + mi * 16 + kq * 4 + r;
                    const int col = tile_n + wc * 64 + ni * 16 + r16;
                    C[(long)row * N + col] = f2b(acc[mi][ni][r] * inv[r]);
                }
        }
    } else if (MODE == 3) {
        ushort_t* C = (ushort_t*)Cv + (long)bz * batchC;
        float* rs = rowsum + (long)bz * 2048;
        #pragma unroll
        for (int mi = 0; mi < 8; mi++)
            #pragma unroll
            for (int r = 0; r < 4; r++) {
                const int row = tile_m + wr * 128 + mi * 16 + kq * 4 + r;
                float psum = 0.f;
                #pragma unroll
                for (int ni = 0; ni < 4; ni++) {
                    const float e = __expf(acc[mi][ni][r] * scale);
                    psum += e;
                    const int col = tile_n + wc * 64 + ni * 16 + r16;
                    C[(long)row * N + col] = f2b(e);
                }
                psum += __shfl_xor(psum, 1);
                psum += __shfl_xor(psum, 2);
                psum += __shfl_xor(psum, 4);
                psum += __shfl_xor(psum, 8);
                if (r16 == 0) atomicAdd(&rs[row], psum);
            }
    } else {
        // MODE 4: fused QKV. Cv = Qb base; sections of MROWS*768 each.
        const int sect  = tile_n / 768;          // 256-tile lies in one section
        const int ncol0 = tile_n - sect * 768;
        if (sect == 2) {
            // V: write TRANSPOSED directly -> Vt[b][d][s]  (Vt passed via rowsum)
            ushort_t* Vt = (ushort_t*)rowsum;
            #pragma unroll
            for (int mi = 0; mi < 8; mi++)
                #pragma unroll
                for (int ni = 0; ni < 4; ni++) {
                    const int row = tile_m + wr * 128 + mi * 16 + kq * 4;
                    const int d   = ncol0 + wc * 64 + ni * 16 + r16;
                    const int b   = row >> 11, s = row & 2047;
                    ushort4 o;
                    o.x = f2b(acc[mi][ni][0]); o.y = f2b(acc[mi][ni][1]);
                    o.z = f2b(acc[mi][ni][2]); o.w = f2b(acc[mi][ni][3]);
                    *(ushort4*)(Vt + (long)b * ((long)2048 * 768) + (long)d * 2048 + s) = o;
                }
        } else {
            ushort_t* C = (ushort_t*)Cv + (size_t)sect * ((size_t)MROWS * 768);
            const float sc = (sect == 0) ? scale : 1.0f;
            #pragma unroll
            for (int mi = 0; mi < 8; mi++)
                #pragma unroll
                for (int ni = 0; ni < 4; ni++)
                    #pragma unroll
                    for (int r = 0; r < 4; r++) {
                        const int row = tile_m + wr * 128 + mi * 16 + kq * 4 + r;
                        const int col = ncol0 + wc * 64 + ni * 16 + r16;
                        C[(long)row * 768 + col] = f2b(acc[mi][ni][r] * sc);
                    }
        }
    }
}

// ---------------------------------------------------------------------------
// m97-structure 128^2 NT GEMM (kept for non-batched ws path)
// ---------------------------------------------------------------------------
template<int MODE>
__global__ __launch_bounds__(256)
void gemm_nt(const ushort_t* __restrict__ A, const ushort_t* __restrict__ Bt,
             void* __restrict__ Cv, int M, int N, int Kd,
             long batchA, long batchB, long batchC, float scale,
             const float* __restrict__ bias, const float* __restrict__ resid,
             float* __restrict__ rowsum)
{
    __shared__ __align__(16) ushort_t As[128 * 32];
    __shared__ __align__(16) ushort_t Bs[128 * 32];

    const int bz = blockIdx.z;
    A  += (long)bz * batchA;
    Bt += (long)bz * batchB;

    const int nxt  = gridDim.x;
    const int nblk = nxt * gridDim.y;
    int lin = blockIdx.y * nxt + blockIdx.x;
    if ((nblk & 7) == 0) {
        const int per = nblk >> 3;
        lin = (lin & 7) * per + (lin >> 3);
    }
    const int tile_n = (lin % nxt) * 128;
    const int tile_m = (lin / nxt) * 128;

    const int tid  = threadIdx.x;
    const int w    = tid >> 6;
    const int lane = tid & 63;
    const int wr = w >> 1, wc = w & 1;
    const int r16 = lane & 15;
    const int kq  = lane >> 4;

    const int srow   = lane >> 2;
    const int schunk = lane & 3;
    const int arow0 = w * 32 + srow;
    const int arow1 = arow0 + 16;
    const int g0 = (schunk ^ ((arow0 >> 1) & 3)) * 8;
    const int g1 = (schunk ^ ((arow1 >> 1) & 3)) * 8;

    const ushort_t* Ar0 = A  + (long)(tile_m + arow0) * Kd + g0;
    const ushort_t* Ar1 = A  + (long)(tile_m + arow1) * Kd + g1;
    const ushort_t* Br0 = Bt + (long)(tile_n + arow0) * Kd + g0;
    const ushort_t* Br1 = Bt + (long)(tile_n + arow1) * Kd + g1;

    ushort_t* lA0 = &As[(w * 32     ) * 32];
    ushort_t* lA1 = &As[(w * 32 + 16) * 32];
    ushort_t* lB0 = &Bs[(w * 32     ) * 32];
    ushort_t* lB1 = &Bs[(w * 32 + 16) * 32];

    f32x4 acc[4][4] = {};

    for (int k0 = 0; k0 < Kd; k0 += 32) {
        gload16(Ar0 + k0, lA0);
        gload16(Ar1 + k0, lA1);
        gload16(Br0 + k0, lB0);
        gload16(Br1 + k0, lB1);
        __syncthreads();

        bf16x8 af[4], bg[4];
        #pragma unroll
        for (int i = 0; i < 4; i++) {
            const int ra = wr * 64 + i * 16 + r16;
            af[i] = *reinterpret_cast<const bf16x8*>(&As[ra * 32 + ((kq ^ ((ra >> 1) & 3)) * 8)]);
            const int rb = wc * 64 + i * 16 + r16;
            bg[i] = *reinterpret_cast<const bf16x8*>(&Bs[rb * 32 + ((kq ^ ((rb >> 1) & 3)) * 8)]);
        }
        #pragma unroll
        for (int mi = 0; mi < 4; mi++)
            #pragma unroll
            for (int ni = 0; ni < 4; ni++)
                acc[mi][ni] = __builtin_amdgcn_mfma_f32_16x16x32_bf16(af[mi], bg[ni], acc[mi][ni], 0, 0, 0);
        __syncthreads();
    }

    if (MODE == 0) {
        ushort_t* C = (ushort_t*)Cv + (long)bz * batchC;
        #pragma unroll
        for (int mi = 0; mi < 4; mi++)
            #pragma unroll
            for (int ni = 0; ni < 4; ni++)
                #pragma unroll
                for (int r = 0; r < 4; r++) {
                    const int row = tile_m + wr * 64 + mi * 16 + kq * 4 + r;
                    const int col = tile_n + wc * 64 + ni * 16 + r16;
                    C[(long)row * N + col] = f2b(acc[mi][ni][r] * scale);
                }
    } else if (MODE == 1) {
        float* C = (float*)Cv;
        #pragma unroll
        for (int mi = 0; mi < 4; mi++)
            #pragma unroll
            for (int ni = 0; ni < 4; ni++)
                #pragma unroll
                for (int r = 0; r < 4; r++) {
                    const int row = tile_m + wr * 64 + mi * 16 + kq * 4 + r;
                    const int col = tile_n + wc * 64 + ni * 16 + r16;
                    C[(long)row * N + col] =
                        acc[mi][ni][r] + bias[col] + resid[(long)row * N + col];
                }
    } else if (MODE == 2) {
        ushort_t* C = (ushort_t*)Cv + (long)bz * batchC;
        const float* rs = rowsum + (long)bz * 2048;
        #pragma unroll
        for (int mi = 0; mi < 4; mi++) {
            float inv[4];
            #pragma unroll
            for (int r = 0; r < 4; r++)
                inv[r] = 1.0f / rs[tile_m + wr * 64 + mi * 16 + kq * 4 + r];
            #pragma unroll
            for (int ni = 0; ni < 4; ni++)
                #pragma unroll
                for (int r = 0; r < 4; r++) {
                    const int row = tile_m + wr * 64 + mi * 16 + kq * 4 + r;
                    const int col = tile_n + wc * 64 + ni * 16 + r16;
                    C[(long)row * N + col] = f2b(acc[mi][ni][r] * inv[r]);
                }
        }
    } else if (MODE == 3) {
        ushort_t* C = (ushort_t*)Cv + (long)bz * batchC;
        float* rs = rowsum + (long)bz * 2048;
        #pragma unroll
        for (int mi = 0; mi < 4; mi++)
            #pragma unroll
            for (int r = 0; r < 4; r++) {
                const int row = tile_m + wr * 64 + mi * 16 + kq * 4 + r;
                float psum = 0.f;
                #pragma unroll
                for (int ni = 0; ni < 4; ni++) {
                    const float e = __expf(acc[mi][ni][r] * scale);
                    psum += e;
                    const int col = tile_n + wc * 64 + ni * 16 + r16;
                    C[(long)row * N + col] = f2b(e);
                }
                psum += __shfl_xor(psum, 1);
                psum += __shfl_xor(psum, 2);
                psum += __shfl_xor(psum, 4);
                psum += __shfl_xor(psum, 8);
                if (r16 == 0) atomicAdd(&rs[row], psum);
            }
    } else {
        const int sect  = tile_n / 768;
        const int ncol0 = tile_n - sect * 768;
        ushort_t* C = (ushort_t*)Cv + (size_t)sect * ((size_t)MROWS * 768);
        const float sc = (sect == 0) ? scale : 1.0f;
        #pragma unroll
        for (int mi = 0; mi < 4; mi++)
            #pragma unroll
            for (int ni = 0; ni < 4; ni++)
                #pragma unroll
                for (int r = 0; r < 4; r++) {
                    const int row = tile_m + wr * 64 + mi * 16 + kq * 4 + r;
                    const int col = ncol0 + wc * 64 + ni * 16 + r16;
                    C[(long)row * 768 + col] = f2b(acc[mi][ni][r] * sc);
                }
    }
}

// ---------------------------------------------------------------------------
// Fallback GEMM (round-3 proven) — only if ws too small for fast paths
// ---------------------------------------------------------------------------
template<int TRANSB, int MODE, int BF32>
__global__ __launch_bounds__(256)
void gemm_s(const ushort_t* __restrict__ A, const void* __restrict__ Bsrc,
            void* __restrict__ Cv, int M, int N, int Kd, float scale,
            const float* __restrict__ bias, const float* __restrict__ resid)
{
    __shared__ __align__(16) ushort_t As[128 * LDST];
    __shared__ __align__(16) ushort_t Bs[128 * LDST];
    const int tile_n = blockIdx.x * 128;
    const int tile_m = blockIdx.y * 128;
    const int tid  = threadIdx.x;
    const int w    = tid >> 6;
    const int lane = tid & 63;
    const int wr = w >> 1, wc = w & 1;
    const int r16 = lane & 15;
    const int kq  = lane >> 4;
    f32x4 acc[4][4] = {};
    for (int k0 = 0; k0 < Kd; k0 += 32) {
        #pragma unroll
        for (int cc = 0; cc < 2; cc++) {
            const int c = tid + cc * 256;
            const int row = c >> 2, col = (c & 3) * 8;
            *(uint4*)&As[row * LDST + col] = *(const uint4*)(A + (long)(tile_m + row) * Kd + k0 + col);
        }
        if (TRANSB == 0) {
            const ushort_t* Bt = (const ushort_t*)Bsrc;
            #pragma unroll
            for (int cc = 0; cc < 2; cc++) {
                const int c = tid + cc * 256;
                const int row = c >> 2, col = (c & 3) * 8;
                *(uint4*)&Bs[row * LDST + col] = *(const uint4*)(Bt + (long)(tile_n + row) * Kd + k0 + col);
            }
        } else {
            #pragma unroll
            for (int i = 0; i < 16; i++) {
                const int lin = i * 256 + tid;
                const int kr = lin >> 7, nc = lin & 127;
                ushort_t bv;
                if (BF32) bv = f2b(((const float*)Bsrc)[(long)(k0 + kr) * N + tile_n + nc]);
                else      bv = ((const ushort_t*)Bsrc)[(long)(k0 + kr) * N + tile_n + nc];
                Bs[nc * LDST + kr] = bv;
            }
        }
        __syncthreads();
        bf16x8 af[4], bg[4];
        #pragma unroll
        for (int i = 0; i < 4; i++) {
            af[i] = *reinterpret_cast<const bf16x8*>(&As[(wr * 64 + i * 16 + r16) * LDST + kq * 8]);
            bg[i] = *reinterpret_cast<const bf16x8*>(&Bs[(wc * 64 + i * 16 + r16) * LDST + kq * 8]);
        }
        #pragma unroll
        for (int mi = 0; mi < 4; mi++)
            #pragma unroll
            for (int ni = 0; ni < 4; ni++)
                acc[mi][ni] = __builtin_amdgcn_mfma_f32_16x16x32_bf16(af[mi], bg[ni], acc[mi][ni], 0, 0, 0);
        __syncthreads();
    }
    if (MODE == 0) {
        ushort_t* C = (ushort_t*)Cv;
        #pragma unroll
        for (int mi = 0; mi < 4; mi++)
            #pragma unroll
            for (int ni = 0; ni < 4; ni++)
                #pragma unroll
                for (int r = 0; r < 4; r++) {
                    const int row = tile_m + wr * 64 + mi * 16 + kq * 4 + r;
                    const int col = tile_n + wc * 64 + ni * 16 + r16;
                    C[(long)row * N + col] = f2b(acc[mi][ni][r] * scale);
                }
    } else {
        float* C = (float*)Cv;
        #pragma unroll
        for (int mi = 0; mi < 4; mi++)
            #pragma unroll
            for (int ni = 0; ni < 4; ni++)
                #pragma unroll
                for (int r = 0; r < 4; r++) {
                    const int row = tile_m + wr * 64 + mi * 16 + kq * 4 + r;
                    const int col = tile_n + wc * 64 + ni * 16 + r16;
                    C[(long)row * N + col] =
                        acc[mi][ni][r] + bias[col] + resid[(long)row * N + col];
                }
    }
}

// softmax over rows of 2048 bf16 (fallback path only)
__global__ void softmax_rows(ushort_t* __restrict__ p)
{
    __shared__ float sm[4], ss_[4];
    ushort_t* pr = p + (long)blockIdx.x * 2048;
    const int tid = threadIdx.x;
    const int w = tid >> 6;
    const uint4 raw = *(const uint4*)(pr + tid * 8);
    float v[8];
    v[0] = b2f((ushort_t)(raw.x & 0xffff)); v[1] = b2f((ushort_t)(raw.x >> 16));
    v[2] = b2f((ushort_t)(raw.y & 0xffff)); v[3] = b2f((ushort_t)(raw.y >> 16));
    v[4] = b2f((ushort_t)(raw.z & 0xffff)); v[5] = b2f((ushort_t)(raw.z >> 16));
    v[6] = b2f((ushort_t)(raw.w & 0xffff)); v[7] = b2f((ushort_t)(raw.w >> 16));
    float mx = -3.0e38f;
    #pragma unroll
    for (int i = 0; i < 8; i++) mx = fmaxf(mx, v[i]);
    #pragma unroll
    for (int off = 32; off; off >>= 1) mx = fmaxf(mx, __shfl_xor(mx, off));
    if ((tid & 63) == 0) sm[w] = mx;
    __syncthreads();
    mx = fmaxf(fmaxf(sm[0], sm[1]), fmaxf(sm[2], sm[3]));
    float s = 0.f;
    #pragma unroll
    for (int i = 0; i < 8; i++) { v[i] = __expf(v[i] - mx); s += v[i]; }
    #pragma unroll
    for (int off = 32; off; off >>= 1) s += __shfl_xor(s, off);
    if ((tid & 63) == 0) ss_[w] = s;
    __syncthreads();
    s = ss_[0] + ss_[1] + ss_[2] + ss_[3];
    const float inv = 1.f / s;
    uint4 o;
    o.x = f2b(v[0] * inv) | ((unsigned)f2b(v[1] * inv) << 16);
    o.y = f2b(v[2] * inv) | ((unsigned)f2b(v[3] * inv) << 16);
    o.z = f2b(v[4] * inv) | ((unsigned)f2b(v[5] * inv) << 16);
    o.w = f2b(v[6] * inv) | ((unsigned)f2b(v[7] * inv) << 16);
    *(uint4*)(pr + tid * 8) = o;
}

// double layernorm per fp32 row of 768, IN PLACE.
// 192 threads x float4 (768 = 192*4): vectorized loads/stores (G13).
__global__ void ln_fused(float* __restrict__ x,
                         const float* __restrict__ w1, const float* __restrict__ b1,
                         const float* __restrict__ w2, const float* __restrict__ b2)
{
    __shared__ float r1s[3], r1q[3], r2s[3], r2q[3];
    const long row = blockIdx.x;
    const int tid = threadIdx.x;
    const int w = tid >> 6;          // 0..2
    float* xr = x + row * 768;
    const float4 v = *(const float4*)(xr + tid * 4);
    float s = v.x + v.y + v.z + v.w;
    float q = v.x * v.x + v.y * v.y + v.z * v.z + v.w * v.w;
    #pragma unroll
    for (int off = 32; off; off >>= 1) { s += __shfl_xor(s, off); q += __shfl_xor(q, off); }
    if ((tid & 63) == 0) { r1s[w] = s; r1q[w] = q; }
    __syncthreads();
    s = r1s[0] + r1s[1] + r1s[2];
    q = r1q[0] + r1q[1] + r1q[2];
    float mu = s * (1.f / 768.f);
    float ri = rsqrtf(q * (1.f / 768.f) - mu * mu + EPS);
    const float4 w1v = *(const float4*)(w1 + tid * 4);
    const float4 b1v = *(const float4*)(b1 + tid * 4);
    float4 y;
    y.x = (v.x - mu) * ri * w1v.x + b1v.x;
    y.y = (v.y - mu) * ri * w1v.y + b1v.y;
    y.z = (v.z - mu) * ri * w1v.z + b1v.z;
    y.w = (v.w - mu) * ri * w1v.w + b1v.w;
    s = y.x + y.y + y.z + y.w;
    q = y.x * y.x + y.y * y.y + y.z * y.z + y.w * y.w;
    #pragma unroll
    for (int off = 32; off; off >>= 1) { s += __shfl_xor(s, off); q += __shfl_xor(q, off); }
    if ((tid & 63) == 0) { r2s[w] = s; r2q[w] = q; }
    __syncthreads();
    s = r2s[0] + r2s[1] + r2s[2];
    q = r2q[0] + r2q[1] + r2q[2];
    mu = s * (1.f / 768.f);
    ri = rsqrtf(q * (1.f / 768.f) - mu * mu + EPS);
    const float4 w2v = *(const float4*)(w2 + tid * 4);
    const float4 b2v = *(const float4*)(b2 + tid * 4);
    float4 o;
    o.x = (y.x - mu) * ri * w2v.x + b2v.x;
    o.y = (y.y - mu) * ri * w2v.y + b2v.y;
    o.z = (y.z - mu) * ri * w2v.z + b2v.z;
    o.w = (y.w - mu) * ri * w2v.w + b2v.w;
    *(float4*)(xr + tid * 4) = o;
}

__global__ void pool_reduce(const float* __restrict__ x, float* __restrict__ pooled)
{
    const int d  = blockIdx.x * 256 + threadIdx.x;
    const int b  = blockIdx.z;
    const int sp = blockIdx.y;
    const float* base = x + ((long)b * 2048 + sp * 128) * 768 + d;
    float s = 0.f;
    #pragma unroll 8
    for (int i = 0; i < 128; i++) s += base[(long)i * 768];
    atomicAdd(&pooled[b * 768 + d], s);
}

// 80 blocks x 64 lanes: one wave per (b, o)
__global__ void logits_kernel(const float* __restrict__ pooled, const float* __restrict__ Wc,
                              const float* __restrict__ bc, float* __restrict__ out)
{
    const int b = blockIdx.x / 10, o = blockIdx.x % 10;
    const int lane = threadIdx.x;
    float s = 0.f;
    #pragma unroll
    for (int d = lane; d < 768; d += 64) s += pooled[b * 768 + d] * Wc[d * 10 + o];
    #pragma unroll
    for (int off = 32; off; off >>= 1) s += __shfl_xor(s, off);
    if (lane == 0) out[b * 10 + o] = s * (1.f / 2048.f) + bc[o];
}

extern "C" void kernel_launch(void* const* d_in, const int* in_sizes, int n_in,
                              void* d_out, int out_size, void* d_ws, size_t ws_size,
                              hipStream_t stream)
{
    (void)in_sizes; (void)n_in; (void)out_size;
    const float* src  = (const float*)d_in[0];
    const float* Wq   = (const float*)d_in[1];
    const float* Wk   = (const float*)d_in[2];
    const float* Wv   = (const float*)d_in[3];
    const float* Wo   = (const float*)d_in[4];
    const float* bo   = (const float*)d_in[5];
    const float* ln1w = (const float*)d_in[6];
    const float* ln1b = (const float*)d_in[7];
    const float* ln2w = (const float*)d_in[8];
    const float* ln2b = (const float*)d_in[9];
    const float* Wc   = (const float*)d_in[10];
    const float* bc   = (const float*)d_in[11];
    float* out = (float*)d_out;

    const dim3 blk(256);
    const dim3 blk192(192);
    const dim3 blk512(512);
    const float qscale = 1.0f / sqrtf(768.0f);
    const long bs = (long)2048 * 768;

    const size_t WT    = (size_t)768 * 768 * 2;          // 256-mult: Wt bufs contiguous
    const size_t BUF   = (size_t)MROWS * 768 * 2;        // 256-mult: Q/K/V contiguous
    const size_t POOLB = 24576;
    const size_t RSB   = (size_t)B_ * 2048 * 4;          // rowsum, 64 KB
    const size_t PROBS8 = (size_t)8 * 2048 * 2048 * 2;
    const size_t needB = 4 * WT + 5 * BUF + POOLB + RSB;  // ~130.7 MB
    const size_t needA = needB + PROBS8;                  // ~197.8 MB

    char* ws = (char*)d_ws;
    size_t off = 0;
    auto alloc = [&](size_t bytes) { void* p = ws + off; off += (bytes + 255) & ~(size_t)255; return p; };

    if (ws_size >= needB) {
        ushort_t* Wtq  = (ushort_t*)alloc(WT);   // Wtq/Wtk/Wtv contiguous => fused QKV B operand
        ushort_t* Wtk  = (ushort_t*)alloc(WT);
        ushort_t* Wtv  = (ushort_t*)alloc(WT);
        ushort_t* Wto  = (ushort_t*)alloc(WT);
        ushort_t* srcb = (ushort_t*)alloc(BUF);
        ushort_t* Qb   = (ushort_t*)alloc(BUF);  // Qb/Kb/Vb contiguous => MODE 4 sect routing
        ushort_t* Kb   = (ushort_t*)alloc(BUF);
        ushort_t* Vb   = (ushort_t*)alloc(BUF);  // untouched by QKV (V goes to Vt); reused as attn
        ushort_t* Vt   = (ushort_t*)alloc(BUF);  // written DIRECTLY by QKV epilogue (transposed)
        float*  pooled = (float*)  alloc(POOLB);
        float*  rowsum = (float*)  alloc(RSB);
        const bool batched = (ws_size >= needA);
        ushort_t* probs = batched ? (ushort_t*)alloc(PROBS8) : srcb;  // srcb dead after QKV
        ushort_t* attn  = Vb;
        float*    xpre  = out + 80;
        (void)Wtk; (void)Wtv;

        // prep: cast + 4 weight transposes + zero(rowsum, pooled) in ONE dispatch
        prep<<<dim3(12952), blk, 0, stream>>>(src, srcb, Wq, Wk, Wv, Wo, Wtq, rowsum, pooled);

        // fused QKV: [16384,768] @ [2304,768]^T; Q/K -> Qb/Kb, V -> Vt (transposed in epilogue)
        gemm256<4><<<dim3(576), blk512, 0, stream>>>(srcb, Wtq, Qb, MROWS, 2304, 768,
                                                     0, 0, 0, qscale, nullptr, nullptr, (float*)Vt);

        if (batched) {
            // scores: exp(QK^T) with fused row-sum atomics; M-stationary decode
            gemm256<3><<<dim3(512), blk512, 0, stream>>>(Qb, Kb, probs, 2048, 2048, 768,
                                                         bs, bs, (long)2048 * 2048, 1.0f,
                                                         nullptr, nullptr, rowsum);
            // PV: normalize by rowsum in epilogue; M-stationary decode
            gemm256<2><<<dim3(192), blk512, 0, stream>>>(probs, Vt, attn, 2048, 768, 2048,
                                                         (long)2048 * 2048, bs, bs, 1.0f,
                                                         nullptr, nullptr, rowsum);
        } else {
            for (int bz = 0; bz < B_; bz += 2) {
                gemm_nt<3><<<dim3(16, 16, 2), blk, 0, stream>>>(Qb + bz * bs, Kb + bz * bs, probs,
                                                                2048, 2048, 768, bs, bs, (long)2048 * 2048,
                                                                1.0f, nullptr, nullptr, rowsum + bz * 2048);
                gemm_nt<2><<<dim3(6, 16, 2), blk, 0, stream>>>(probs, Vt + bz * bs, attn + bz * bs,
                                                               2048, 768, 2048,
                                                               (long)2048 * 2048, bs, bs, 1.0f,
                                                               nullptr, nullptr, rowsum + bz * 2048);
            }
        }

        gemm256<1><<<dim3(192), blk512, 0, stream>>>(attn, Wto, xpre, MROWS, 768, 768,
                                                     0, 0, 0, 1.0f, bo, src, nullptr);
        ln_fused<<<MROWS, blk192, 0, stream>>>(xpre, ln1w, ln1b, ln2w, ln2b);
        pool_reduce<<<dim3(3, 16, B_), blk, 0, stream>>>(xpre, pooled);
        logits_kernel<<<80, 64, 0, stream>>>(pooled, Wc, bc, out);
    } else {
        // round-3 proven fallback (~100.7 MB)
        ushort_t* srcb = (ushort_t*)alloc(BUF);
        ushort_t* Qb   = (ushort_t*)alloc(BUF);
        ushort_t* Kb   = (ushort_t*)alloc(BUF);
        ushort_t* Vb   = (ushort_t*)alloc(BUF);
        float*  pooled = (float*)  alloc(POOLB);
        ushort_t* probs = srcb;
        ushort_t* attn  = Qb;
        float*    xpre  = out + 80;

        cast_f32_bf16<<<MROWS * 768 / 1024, blk, 0, stream>>>(src, srcb, (long)MROWS * 768);
        gemm_s<1, 0, 1><<<dim3(6, 128), blk, 0, stream>>>(srcb, Wq, Qb, MROWS, 768, 768, qscale, nullptr, nullptr);
        gemm_s<1, 0, 1><<<dim3(6, 128), blk, 0, stream>>>(srcb, Wk, Kb, MROWS, 768, 768, 1.0f, nullptr, nullptr);
        gemm_s<1, 0, 1><<<dim3(6, 128), blk, 0, stream>>>(srcb, Wv, Vb, MROWS, 768, 768, 1.0f, nullptr, nullptr);
        for (int bz = 0; bz < B_; bz++) {
            gemm_s<0, 0, 0><<<dim3(16, 16), blk, 0, stream>>>(Qb + bz * bs, Kb + bz * bs, probs,
                                                              2048, 2048, 768, 1.0f, nullptr, nullptr);
            softmax_rows<<<2048, blk, 0, stream>>>(probs);
            gemm_s<1, 0, 0><<<dim3(6, 16), blk, 0, stream>>>(probs, Vb + bz * bs, attn + bz * bs,
                                                             2048, 768, 2048, 1.0f, nullptr, nullptr);
        }
        gemm_s<1, 1, 1><<<dim3(6, 128), blk, 0, stream>>>(attn, Wo, xpre, MROWS, 768, 768, 1.0f, bo, src);
        ln_fused<<<MROWS, blk192, 0, stream>>>(xpre, ln1w, ln1b, ln2w, ln2b);
        hipMemsetAsync(pooled, 0, B_ * 768 * 4, stream);
        pool_reduce<<<dim3(3, 16, B_), blk, 0, stream>>>(xpre, pooled);
        logits_kernel<<<80, 64, 0, stream>>>(pooled, Wc, bc, out);
    }
}